// Round 3
// baseline (4497.598 us; speedup 1.0000x reference)
//
#include <hip/hip_runtime.h>
#include <hip/hip_bf16.h>
#include <math.h>

#define N_NODES   100000
#define N_EDGES   3200000
#define IN_DIM    128
#define HID       64
#define OUT_DIM   10
#define N_GRAPHS  64

// Coarse bucketing: bucket = row >> 7 (128 rows per bucket)
#define BUCKET_SHIFT 7
#define BUCKET_ROWS  128
#define NBUCKET ((N_NODES + BUCKET_ROWS - 1) >> BUCKET_SHIFT)     // 782
#define TILE_EDGES 4096                                           // 256 thr x 16
#define NTILES ((N_EDGES + TILE_EDGES - 1) / TILE_EDGES)          // 782
#define NH (NBUCKET * NTILES)                                     // 611,524
#define NSCAN1 ((NH + 1023) / 1024)                               // 598

typedef unsigned long long ull;

// ---------------------------------------------------------------- pass 1
// Per-tile LDS histogram over coarse buckets; write hist[bucket][tile]
// (bucket-major so the scan below is a flat coalesced exclusive scan).
__global__ __launch_bounds__(256) void hist_pass(const int* __restrict__ rows,
                                                 int* __restrict__ hist) {
    __shared__ int h[NBUCKET];
    int tid = threadIdx.x, tile = blockIdx.x;
    for (int i = tid; i < NBUCKET; i += 256) h[i] = 0;
    __syncthreads();
    int base = tile * TILE_EDGES;
#pragma unroll
    for (int i = 0; i < 16; i++) {
        int e = base + i * 256 + tid;
        if (e < N_EDGES) atomicAdd(&h[rows[e] >> BUCKET_SHIFT], 1);
    }
    __syncthreads();
    for (int i = tid; i < NBUCKET; i += 256) hist[i * NTILES + tile] = h[i];
}

// ---------------------------------------------------------------- scan
// Generic chunked exclusive scan: 256 thr x 4 elems. In-place safe (each
// location read+written by the same thread; cross-thread flow via LDS).
__global__ __launch_bounds__(256) void scan_blocks(const int* __restrict__ in,
                                                   int* __restrict__ out,
                                                   int* __restrict__ blk, int n) {
    __shared__ int sdata[256];
    int t = threadIdx.x;
    int base = blockIdx.x * 1024 + t * 4;
    int v[4];
#pragma unroll
    for (int i = 0; i < 4; i++) {
        int idx = base + i;
        v[i] = (idx < n) ? in[idx] : 0;
    }
    int s = v[0] + v[1] + v[2] + v[3];
    sdata[t] = s;
    __syncthreads();
    for (int off = 1; off < 256; off <<= 1) {
        int x = (t >= off) ? sdata[t - off] : 0;
        __syncthreads();
        sdata[t] += x;
        __syncthreads();
    }
    int excl = sdata[t] - s;
#pragma unroll
    for (int i = 0; i < 4; i++) {
        int idx = base + i;
        if (idx < n) { out[idx] = excl; excl += v[i]; }
    }
    if (t == 255) blk[blockIdx.x] = sdata[255];
}

__global__ __launch_bounds__(256) void scan_add(int* __restrict__ data,
                                                const int* __restrict__ blk, int n) {
    int i = blockIdx.x * 256 + threadIdx.x;
    if (i < n) data[i] += blk[i >> 10];
}

// ---------------------------------------------------------------- pass 2
// Re-read edges; claim positions via block-local LDS cursors seeded from the
// scanned histogram; write packed 8B records. No global atomics; each output
// line is touched by <=2 blocks.
__global__ __launch_bounds__(256) void scatter_pass(const int* __restrict__ rows,
                                                    const int* __restrict__ cols,
                                                    const float* __restrict__ vals,
                                                    const int* __restrict__ histScan,
                                                    ull* __restrict__ edata) {
    __shared__ int cur[NBUCKET];
    int tid = threadIdx.x, tile = blockIdx.x;
    for (int i = tid; i < NBUCKET; i += 256) cur[i] = histScan[i * NTILES + tile];
    __syncthreads();
    int base = tile * TILE_EDGES;
#pragma unroll
    for (int i = 0; i < 16; i++) {
        int e = base + i * 256 + tid;
        if (e < N_EDGES) {
            int r = rows[e];
            int b = r >> BUCKET_SHIFT;
            int pos = atomicAdd(&cur[b], 1);      // LDS atomic, block-local
            unsigned hi = ((unsigned)(r & (BUCKET_ROWS - 1)) << 24) | (unsigned)cols[e];
            ull pk = ((ull)hi << 32) | (ull)__float_as_uint(vals[e]);
            edata[pos] = pk;
        }
    }
}

// ------------------------------------------------------------------- GEMM
// H[n][c] = sum_k X[n][k] * W[c][k] + b[c].  Thread = row x 16 channels;
// blockIdx.y picks channel group so W stays wave-uniform (s_loads).
template <int IN, int CPT>
__global__ __launch_bounds__(256) void gemm_bias(const float* __restrict__ X,
                                                 const float* __restrict__ W,
                                                 const float* __restrict__ B,
                                                 float* __restrict__ H) {
    int row = blockIdx.x * 256 + threadIdx.x;
    int c0 = blockIdx.y * CPT;
    if (row >= N_NODES) return;
    float acc[CPT];
#pragma unroll
    for (int c = 0; c < CPT; c++) acc[c] = B[c0 + c];
    const float4* X4 = reinterpret_cast<const float4*>(X + (size_t)row * IN);
    for (int k0 = 0; k0 < IN; k0 += 16) {
        float x[16];
#pragma unroll
        for (int i = 0; i < 4; i++) {
            float4 t = X4[(k0 >> 2) + i];
            x[i * 4 + 0] = t.x; x[i * 4 + 1] = t.y;
            x[i * 4 + 2] = t.z; x[i * 4 + 3] = t.w;
        }
#pragma unroll
        for (int c = 0; c < CPT; c++) {
            const float* w = W + (c0 + c) * IN + k0;
#pragma unroll
            for (int k = 0; k < 16; k++) acc[c] += x[k] * w[k];
        }
    }
    float4* out = reinterpret_cast<float4*>(H + (size_t)row * HID + c0);
#pragma unroll
    for (int c = 0; c < CPT; c += 4) {
        float4 o; o.x = acc[c]; o.y = acc[c+1]; o.z = acc[c+2]; o.w = acc[c+3];
        out[c >> 2] = o;
    }
}

// ------------------------------------------------------------------- SpMM
// One 512-thr block per bucket. 128x64 fp32 accumulator in LDS (32 KB).
// 8 waves stream the bucket's edges: scalar (wave-uniform) packed-edge loads,
// 8-deep unrolled vector gathers, fire-and-forget workgroup-scope LDS f32
// atomics. Then one coalesced write with relu + Hsum accumulation.
template <int MODE>
__global__ __launch_bounds__(512) void spmm_bucket(const int* __restrict__ histScan,
                                                   const ull* __restrict__ edata,
                                                   const float* __restrict__ Hin,
                                                   float* __restrict__ Xout,
                                                   float* __restrict__ Hsum) {
    __shared__ float acc[BUCKET_ROWS * HID];   // 32 KB
    int b = blockIdx.x;
    int tid = threadIdx.x;
    int lane = tid & 63;
    int s = histScan[b * NTILES];
    int e = (b + 1 < NBUCKET) ? histScan[(b + 1) * NTILES] : N_EDGES;
    for (int i = tid; i < BUCKET_ROWS * HID; i += 512) acc[i] = 0.f;
    __syncthreads();

    int wv = __builtin_amdgcn_readfirstlane(tid >> 6);   // wave-uniform
    int cnt = e - s;
    int chunk = (cnt + 7) >> 3;
    int js = s + wv * chunk;
    int je = js + chunk; if (je > e) je = e;

    int j = js;
    for (; j + 8 <= je; j += 8) {
        ull p[8];
#pragma unroll
        for (int i = 0; i < 8; i++) p[i] = edata[j + i];
        float g[8];
#pragma unroll
        for (int i = 0; i < 8; i++) {
            int c = (int)((unsigned)(p[i] >> 32) & 0xFFFFFFu);
            g[i] = Hin[c * HID + lane];
        }
#pragma unroll
        for (int i = 0; i < 8; i++) {
            int rl = (int)(unsigned)(p[i] >> 56);
            float v = __uint_as_float((unsigned)p[i]);
            __hip_atomic_fetch_add(&acc[rl * HID + lane], v * g[i],
                                   __ATOMIC_RELAXED, __HIP_MEMORY_SCOPE_WORKGROUP);
        }
    }
    for (; j < je; j++) {
        ull p = edata[j];
        int c = (int)((unsigned)(p >> 32) & 0xFFFFFFu);
        int rl = (int)(unsigned)(p >> 56);
        float v = __uint_as_float((unsigned)p);
        __hip_atomic_fetch_add(&acc[rl * HID + lane], v * Hin[c * HID + lane],
                               __ATOMIC_RELAXED, __HIP_MEMORY_SCOPE_WORKGROUP);
    }
    __syncthreads();

    int rbase = b * BUCKET_ROWS;
    for (int i = tid; i < BUCKET_ROWS * HID; i += 512) {
        int grow = rbase + (i >> 6);
        if (grow < N_NODES) {
            float val = fmaxf(acc[i], 0.f);
            size_t gi = (size_t)grow * HID + (i & 63);
            if (MODE == 1)      { Xout[gi] = val; Hsum[gi] = val; }
            else if (MODE == 2) { Xout[gi] = val; Hsum[gi] += val; }
            else                { Hsum[gi] += val; }
        }
    }
}

// ------------------------------------------------------------------- Pool
__global__ __launch_bounds__(128) void find_starts(const int* __restrict__ batch,
                                                   int* __restrict__ starts) {
    int g = threadIdx.x;
    if (g > N_GRAPHS) return;
    if (g == N_GRAPHS) { starts[g] = N_NODES; return; }
    int lo = 0, hi = N_NODES;
    while (lo < hi) {
        int mid = (lo + hi) >> 1;
        if (batch[mid] < g) lo = mid + 1; else hi = mid;
    }
    starts[g] = lo;
}

__global__ __launch_bounds__(256) void pool_kernel(const float* __restrict__ Hsum,
                                                   const int* __restrict__ starts,
                                                   float* __restrict__ pooled) {
    __shared__ float red[4][HID];
    int g = blockIdx.x;
    int lane = threadIdx.x & 63;
    int w = threadIdx.x >> 6;
    int s = starts[g], epos = starts[g + 1];
    float acc = 0.f;
    for (int n = s + w; n < epos; n += 4) acc += Hsum[(size_t)n * HID + lane];
    red[w][lane] = acc;
    __syncthreads();
    if (w == 0) {
        float tot = red[0][lane] + red[1][lane] + red[2][lane] + red[3][lane];
        int cntg = epos - s;
        float denom = 3.0f * (float)(cntg > 1 ? cntg : 1);
        pooled[g * HID + lane] = tot / denom;
    }
}

// ------------------------------------------------------------------- Head
__global__ __launch_bounds__(64) void head_kernel(const float* __restrict__ pooled,
                                                  const float* __restrict__ Wout,
                                                  const float* __restrict__ bout,
                                                  float* __restrict__ out) {
    int g = blockIdx.x;
    int t = threadIdx.x;
    __shared__ float pr[HID];
    __shared__ float lg[OUT_DIM];
    __shared__ float mx, sm;
    pr[t] = pooled[g * HID + t];
    __syncthreads();
    if (t < OUT_DIM) {
        float a = bout[t];
        for (int k = 0; k < HID; k++) a += pr[k] * Wout[t * HID + k];
        lg[t] = a;
    }
    __syncthreads();
    if (t == 0) {
        float m = lg[0];
        for (int j = 1; j < OUT_DIM; j++) m = fmaxf(m, lg[j]);
        float s = 0.f;
        for (int j = 0; j < OUT_DIM; j++) s += expf(lg[j] - m);
        mx = m; sm = s;
    }
    __syncthreads();
    if (t < OUT_DIM) out[g * OUT_DIM + t] = expf(lg[t] - mx) / sm;
}

// ---------------------------------------------------------------- launcher
extern "C" void kernel_launch(void* const* d_in, const int* in_sizes, int n_in,
                              void* d_out, int out_size, void* d_ws, size_t ws_size,
                              hipStream_t stream) {
    const float* X    = (const float*)d_in[0];
    const float* vals = (const float*)d_in[1];
    const float* W1   = (const float*)d_in[2];
    const float* b1   = (const float*)d_in[3];
    const float* W2   = (const float*)d_in[4];
    const float* b2   = (const float*)d_in[5];
    const float* W3   = (const float*)d_in[6];
    const float* b3   = (const float*)d_in[7];
    const float* Wout = (const float*)d_in[8];
    const float* bout = (const float*)d_in[9];
    const int*   rows = (const int*)d_in[10];
    const int*   cols = (const int*)d_in[11];
    const int*   batch= (const int*)d_in[12];
    float* out = (float*)d_out;

    char* p = (char*)d_ws;
    auto carve = [&](size_t bytes) {
        void* q = (void*)p;
        p += (bytes + 255) & ~(size_t)255;
        return q;
    };
    float* h      = (float*)carve((size_t)N_NODES * HID * 4);
    float* Xc     = (float*)carve((size_t)N_NODES * HID * 4);
    float* hsum   = (float*)carve((size_t)N_NODES * HID * 4);
    int*   hist   = (int*)  carve((size_t)NH * 4);
    int*   blkA   = (int*)  carve(1024 * 4);
    int*   blkB   = (int*)  carve(1024 * 4);
    int*   starts = (int*)  carve((N_GRAPHS + 1) * 4);
    float* pooled = (float*)carve(N_GRAPHS * HID * 4);
    ull*   edata  = (ull*)  carve((size_t)N_EDGES * 8);
    (void)ws_size; (void)in_sizes; (void)n_in; (void)out_size;

    // ---- CSR-ish build: coarse bucket grouping, zero global atomics
    hist_pass<<<NTILES, 256, 0, stream>>>(rows, hist);
    scan_blocks<<<NSCAN1, 256, 0, stream>>>(hist, hist, blkA, NH);
    scan_blocks<<<1, 256, 0, stream>>>(blkA, blkA, blkB, NSCAN1);
    scan_add<<<(NH + 255) / 256, 256, 0, stream>>>(hist, blkA, NH);
    scatter_pass<<<NTILES, 256, 0, stream>>>(rows, cols, vals, hist, edata);

    const dim3 gemm_grid((N_NODES + 255) / 256, HID / 16);

    // ---- layer 1
    gemm_bias<IN_DIM, 16><<<gemm_grid, 256, 0, stream>>>(X, W1, b1, h);
    spmm_bucket<1><<<NBUCKET, 512, 0, stream>>>(hist, edata, h, Xc, hsum);
    // ---- layer 2
    gemm_bias<HID, 16><<<gemm_grid, 256, 0, stream>>>(Xc, W2, b2, h);
    spmm_bucket<2><<<NBUCKET, 512, 0, stream>>>(hist, edata, h, Xc, hsum);
    // ---- layer 3
    gemm_bias<HID, 16><<<gemm_grid, 256, 0, stream>>>(Xc, W3, b3, h);
    spmm_bucket<3><<<NBUCKET, 512, 0, stream>>>(hist, edata, h, Xc, hsum);

    // ---- pool + head
    find_starts<<<1, 128, 0, stream>>>(batch, starts);
    pool_kernel<<<N_GRAPHS, 256, 0, stream>>>(hsum, starts, pooled);
    head_kernel<<<N_GRAPHS, 64, 0, stream>>>(pooled, Wout, bout, out);
}

// Round 4
// 766.780 us; speedup vs baseline: 5.8656x; 5.8656x over previous
//
#include <hip/hip_runtime.h>
#include <hip/hip_bf16.h>
#include <math.h>

#define N_NODES   100000
#define N_EDGES   3200000
#define IN_DIM    128
#define HID       64
#define OUT_DIM   10
#define N_GRAPHS  64

// Coarse bucketing: bucket = row >> 7 (128 rows/bucket)
#define BUCKET_SHIFT 7
#define BUCKET_ROWS  128
#define NBUCKET ((N_NODES + BUCKET_ROWS - 1) >> BUCKET_SHIFT)     // 782
#define TILE_EDGES 8192                                           // 256 thr x 32
#define NTILES ((N_EDGES + TILE_EDGES - 1) / TILE_EDGES)          // 391
#define NH (NBUCKET * NTILES)                                     // 305,762
#define NSCAN1 ((NH + 1023) / 1024)                               // 299

typedef unsigned long long ull;

// ---------------------------------------------------------------- pass A
// Per-tile LDS histogram over coarse buckets -> hist[bucket][tile]
// (bucket-major so the flat exclusive scan gives bucket-grouped offsets).
__global__ __launch_bounds__(256) void hist_pass(const int* __restrict__ rows,
                                                 int* __restrict__ hist) {
    __shared__ int h[NBUCKET];
    int tid = threadIdx.x, tile = blockIdx.x;
    for (int i = tid; i < NBUCKET; i += 256) h[i] = 0;
    __syncthreads();
    int base = tile * TILE_EDGES;
#pragma unroll
    for (int i = 0; i < 32; i++) {
        int e = base + i * 256 + tid;
        if (e < N_EDGES) atomicAdd(&h[rows[e] >> BUCKET_SHIFT], 1);
    }
    __syncthreads();
    for (int i = tid; i < NBUCKET; i += 256) hist[i * NTILES + tile] = h[i];
}

// ---------------------------------------------------------------- scan
__global__ __launch_bounds__(256) void scan_blocks(const int* __restrict__ in,
                                                   int* __restrict__ out,
                                                   int* __restrict__ blk, int n) {
    __shared__ int sdata[256];
    int t = threadIdx.x;
    int base = blockIdx.x * 1024 + t * 4;
    int v[4];
#pragma unroll
    for (int i = 0; i < 4; i++) {
        int idx = base + i;
        v[i] = (idx < n) ? in[idx] : 0;
    }
    int s = v[0] + v[1] + v[2] + v[3];
    sdata[t] = s;
    __syncthreads();
    for (int off = 1; off < 256; off <<= 1) {
        int x = (t >= off) ? sdata[t - off] : 0;
        __syncthreads();
        sdata[t] += x;
        __syncthreads();
    }
    int excl = sdata[t] - s;
#pragma unroll
    for (int i = 0; i < 4; i++) {
        int idx = base + i;
        if (idx < n) { out[idx] = excl; excl += v[i]; }
    }
    if (t == 255) blk[blockIdx.x] = sdata[255];
}

__global__ __launch_bounds__(256) void scan_add(int* __restrict__ data,
                                                const int* __restrict__ blk, int n) {
    int i = blockIdx.x * 256 + threadIdx.x;
    if (i < n) data[i] += blk[i >> 10];
}

// ---------------------------------------------------------------- pass B
// Re-read edges; block-local LDS cursors seeded from the scanned histogram;
// write bucket-grouped packed records (rowLocal<<56 | col<<32 | val).
// No global atomics; each output line shared by <=2 blocks.
__global__ __launch_bounds__(256) void scatter_pass(const int* __restrict__ rows,
                                                    const int* __restrict__ cols,
                                                    const float* __restrict__ vals,
                                                    const int* __restrict__ histScan,
                                                    ull* __restrict__ etmp) {
    __shared__ int cur[NBUCKET];
    int tid = threadIdx.x, tile = blockIdx.x;
    for (int i = tid; i < NBUCKET; i += 256) cur[i] = histScan[i * NTILES + tile];
    __syncthreads();
    int base = tile * TILE_EDGES;
#pragma unroll
    for (int i = 0; i < 32; i++) {
        int e = base + i * 256 + tid;
        if (e < N_EDGES) {
            int r = rows[e];
            int b = r >> BUCKET_SHIFT;
            int pos = atomicAdd(&cur[b], 1);      // LDS atomic, block-local
            unsigned hi = ((unsigned)(r & (BUCKET_ROWS - 1)) << 24) | (unsigned)cols[e];
            etmp[pos] = ((ull)hi << 32) | (ull)__float_as_uint(vals[e]);
        }
    }
}

// ---------------------------------------------------------------- pass C
// One block per bucket: counting-sort the bucket's contiguous ~4k edges by
// local row (LDS counters, same-L2-domain writes), emit exact row_ptr and
// R2-format packed edges (val<<32 | col).
__global__ __launch_bounds__(256) void bucket_sort(const int* __restrict__ histScan,
                                                   const ull* __restrict__ etmp,
                                                   ull* __restrict__ edges,
                                                   int* __restrict__ row_ptr) {
    __shared__ int rcnt[BUCKET_ROWS];
    __shared__ int roff[BUCKET_ROWS];
    __shared__ int rcur[BUCKET_ROWS];
    int b = blockIdx.x, t = threadIdx.x;
    int s = histScan[b * NTILES];
    int e = (b + 1 < NBUCKET) ? histScan[(b + 1) * NTILES] : N_EDGES;
    if (t < BUCKET_ROWS) rcnt[t] = 0;
    __syncthreads();
    for (int j = s + t; j < e; j += 256)
        atomicAdd(&rcnt[(int)(etmp[j] >> 56)], 1);
    __syncthreads();
    if (t < BUCKET_ROWS) roff[t] = rcnt[t];
    __syncthreads();
    for (int off = 1; off < BUCKET_ROWS; off <<= 1) {
        int x = (t >= off && t < BUCKET_ROWS) ? roff[t - off] : 0;
        __syncthreads();
        if (t < BUCKET_ROWS) roff[t] += x;
        __syncthreads();
    }
    if (t < BUCKET_ROWS) {
        int excl = roff[t] - rcnt[t];
        rcur[t] = s + excl;
        int grow = b * BUCKET_ROWS + t;
        if (grow < N_NODES) row_ptr[grow] = s + excl;
    }
    if (b == NBUCKET - 1 && t == 0) row_ptr[N_NODES] = N_EDGES;
    __syncthreads();
    for (int j = s + t; j < e; j += 256) {
        ull p = etmp[j];
        int rl = (int)(p >> 56);
        unsigned col = (unsigned)(p >> 32) & 0xFFFFFFu;
        int pos = atomicAdd(&rcur[rl], 1);        // LDS atomic
        edges[pos] = ((p & 0xFFFFFFFFull) << 32) | (ull)col;
    }
}

// ------------------------------------------------------------------- GEMM
// H[n][c] = sum_k X[n][k]*W[c][k] + b[c]; output bf16 (RNE). Thread = row x
// 16 channels; blockIdx.y picks channel group so W stays wave-uniform.
template <int IN, int CPT>
__global__ __launch_bounds__(256) void gemm_bias(const float* __restrict__ X,
                                                 const float* __restrict__ W,
                                                 const float* __restrict__ B,
                                                 unsigned short* __restrict__ H) {
    int row = blockIdx.x * 256 + threadIdx.x;
    int c0 = blockIdx.y * CPT;
    if (row >= N_NODES) return;
    float acc[CPT];
#pragma unroll
    for (int c = 0; c < CPT; c++) acc[c] = B[c0 + c];
    const float4* X4 = reinterpret_cast<const float4*>(X + (size_t)row * IN);
    for (int k0 = 0; k0 < IN; k0 += 16) {
        float x[16];
#pragma unroll
        for (int i = 0; i < 4; i++) {
            float4 t = X4[(k0 >> 2) + i];
            x[i * 4 + 0] = t.x; x[i * 4 + 1] = t.y;
            x[i * 4 + 2] = t.z; x[i * 4 + 3] = t.w;
        }
#pragma unroll
        for (int c = 0; c < CPT; c++) {
            const float* w = W + (c0 + c) * IN + k0;
#pragma unroll
            for (int k = 0; k < 16; k++) acc[c] += x[k] * w[k];
        }
    }
    unsigned pk[CPT / 2];
#pragma unroll
    for (int c = 0; c < CPT; c += 2) {
        unsigned b0 = __float_as_uint(acc[c]);
        unsigned b1 = __float_as_uint(acc[c + 1]);
        b0 = (b0 + 0x7fffu + ((b0 >> 16) & 1u)) >> 16;   // RNE to bf16
        b1 = (b1 + 0x7fffu + ((b1 >> 16) & 1u)) >> 16;
        pk[c >> 1] = b0 | (b1 << 16);
    }
    uint4* out = reinterpret_cast<uint4*>(H + (size_t)row * HID + c0);
    out[0] = make_uint4(pk[0], pk[1], pk[2], pk[3]);
    out[1] = make_uint4(pk[4], pk[5], pk[6], pk[7]);
}

// ------------------------------------------------------------------- SpMM
// Row-per-wave, lane = feature, bf16 gathers (128B/edge), 8-deep unroll.
template <int MODE>
__global__ __launch_bounds__(256) void spmm_relu(const int* __restrict__ row_ptr,
                                                 const ull* __restrict__ edges,
                                                 const unsigned short* __restrict__ Hin,
                                                 float* __restrict__ Xout,
                                                 float* __restrict__ Hsum) {
    int wid  = (blockIdx.x * 256 + threadIdx.x) >> 6;
    int lane = threadIdx.x & 63;
    if (wid >= N_NODES) return;
    int r = __builtin_amdgcn_readfirstlane(wid);  // wave-uniform -> s_loads
    int start = row_ptr[r];
    int end   = row_ptr[r + 1];
    float acc = 0.f;
    int e = start;
    for (; e + 8 <= end; e += 8) {
        ull p[8];
#pragma unroll
        for (int i = 0; i < 8; i++) p[i] = edges[e + i];
        float h[8];
#pragma unroll
        for (int i = 0; i < 8; i++) {
            int c = (int)(unsigned)(p[i] & 0xFFFFFFFFull);
            h[i] = __uint_as_float((unsigned)Hin[c * HID + lane] << 16);
        }
#pragma unroll
        for (int i = 0; i < 8; i++) {
            float v = __uint_as_float((unsigned)(p[i] >> 32));
            acc += v * h[i];
        }
    }
    for (; e < end; e++) {
        ull p = edges[e];
        int c = (int)(unsigned)(p & 0xFFFFFFFFull);
        float v = __uint_as_float((unsigned)(p >> 32));
        acc += v * __uint_as_float((unsigned)Hin[c * HID + lane] << 16);
    }
    float val = fmaxf(acc, 0.f);
    int idx = r * HID + lane;
    if (MODE == 1)      { Xout[idx] = val; Hsum[idx] = val; }
    else if (MODE == 2) { Xout[idx] = val; Hsum[idx] += val; }
    else                { Hsum[idx] += val; }
}

// ------------------------------------------------------------------- Pool
__global__ __launch_bounds__(128) void find_starts(const int* __restrict__ batch,
                                                   int* __restrict__ starts) {
    int g = threadIdx.x;
    if (g > N_GRAPHS) return;
    if (g == N_GRAPHS) { starts[g] = N_NODES; return; }
    int lo = 0, hi = N_NODES;
    while (lo < hi) {
        int mid = (lo + hi) >> 1;
        if (batch[mid] < g) lo = mid + 1; else hi = mid;
    }
    starts[g] = lo;
}

__global__ __launch_bounds__(256) void pool_kernel(const float* __restrict__ Hsum,
                                                   const int* __restrict__ starts,
                                                   float* __restrict__ pooled) {
    __shared__ float red[4][HID];
    int g = blockIdx.x;
    int lane = threadIdx.x & 63;
    int w = threadIdx.x >> 6;
    int s = starts[g], epos = starts[g + 1];
    float acc = 0.f;
    for (int n = s + w; n < epos; n += 4) acc += Hsum[(size_t)n * HID + lane];
    red[w][lane] = acc;
    __syncthreads();
    if (w == 0) {
        float tot = red[0][lane] + red[1][lane] + red[2][lane] + red[3][lane];
        int cntg = epos - s;
        float denom = 3.0f * (float)(cntg > 1 ? cntg : 1);
        pooled[g * HID + lane] = tot / denom;
    }
}

// ------------------------------------------------------------------- Head
__global__ __launch_bounds__(64) void head_kernel(const float* __restrict__ pooled,
                                                  const float* __restrict__ Wout,
                                                  const float* __restrict__ bout,
                                                  float* __restrict__ out) {
    int g = blockIdx.x;
    int t = threadIdx.x;
    __shared__ float pr[HID];
    __shared__ float lg[OUT_DIM];
    __shared__ float mx, sm;
    pr[t] = pooled[g * HID + t];
    __syncthreads();
    if (t < OUT_DIM) {
        float a = bout[t];
        for (int k = 0; k < HID; k++) a += pr[k] * Wout[t * HID + k];
        lg[t] = a;
    }
    __syncthreads();
    if (t == 0) {
        float m = lg[0];
        for (int j = 1; j < OUT_DIM; j++) m = fmaxf(m, lg[j]);
        float s = 0.f;
        for (int j = 0; j < OUT_DIM; j++) s += expf(lg[j] - m);
        mx = m; sm = s;
    }
    __syncthreads();
    if (t < OUT_DIM) out[g * OUT_DIM + t] = expf(lg[t] - mx) / sm;
}

// ---------------------------------------------------------------- launcher
extern "C" void kernel_launch(void* const* d_in, const int* in_sizes, int n_in,
                              void* d_out, int out_size, void* d_ws, size_t ws_size,
                              hipStream_t stream) {
    const float* X    = (const float*)d_in[0];
    const float* vals = (const float*)d_in[1];
    const float* W1   = (const float*)d_in[2];
    const float* b1   = (const float*)d_in[3];
    const float* W2   = (const float*)d_in[4];
    const float* b2   = (const float*)d_in[5];
    const float* W3   = (const float*)d_in[6];
    const float* b3   = (const float*)d_in[7];
    const float* Wout = (const float*)d_in[8];
    const float* bout = (const float*)d_in[9];
    const int*   rows = (const int*)d_in[10];
    const int*   cols = (const int*)d_in[11];
    const int*   batch= (const int*)d_in[12];
    float* out = (float*)d_out;

    char* p = (char*)d_ws;
    auto carve = [&](size_t bytes) {
        void* q = (void*)p;
        p += (bytes + 255) & ~(size_t)255;
        return q;
    };
    unsigned short* h = (unsigned short*)carve((size_t)N_NODES * HID * 2);
    float* Xc     = (float*)carve((size_t)N_NODES * HID * 4);
    float* hsum   = (float*)carve((size_t)N_NODES * HID * 4);
    int*   hist   = (int*)  carve((size_t)NH * 4);
    int*   row_ptr= (int*)  carve((size_t)(N_NODES + 1) * 4);
    int*   blkA   = (int*)  carve(1024 * 4);
    int*   blkB   = (int*)  carve(1024 * 4);
    int*   starts = (int*)  carve((N_GRAPHS + 1) * 4);
    float* pooled = (float*)carve(N_GRAPHS * HID * 4);
    ull*   edges  = (ull*)  carve((size_t)N_EDGES * 8);
    // etmp aliases Xc: etmp dead before the first spmm writes Xc.
    ull*   etmp   = (ull*)Xc;
    (void)ws_size; (void)in_sizes; (void)n_in; (void)out_size;

    // ---- build: histogram -> scan -> bucket-grouped scatter -> local sort
    hist_pass<<<NTILES, 256, 0, stream>>>(rows, hist);
    scan_blocks<<<NSCAN1, 256, 0, stream>>>(hist, hist, blkA, NH);
    scan_blocks<<<1, 256, 0, stream>>>(blkA, blkA, blkB, NSCAN1);
    scan_add<<<(NH + 255) / 256, 256, 0, stream>>>(hist, blkA, NH);
    scatter_pass<<<NTILES, 256, 0, stream>>>(rows, cols, vals, hist, etmp);
    bucket_sort<<<NBUCKET, 256, 0, stream>>>(hist, etmp, edges, row_ptr);

    const dim3 gemm_grid((N_NODES + 255) / 256, HID / 16);
    const int  spmm_grid = (N_NODES + 3) / 4;

    // ---- layer 1
    gemm_bias<IN_DIM, 16><<<gemm_grid, 256, 0, stream>>>(X, W1, b1, h);
    spmm_relu<1><<<spmm_grid, 256, 0, stream>>>(row_ptr, edges, h, Xc, hsum);
    // ---- layer 2
    gemm_bias<HID, 16><<<gemm_grid, 256, 0, stream>>>(Xc, W2, b2, h);
    spmm_relu<2><<<spmm_grid, 256, 0, stream>>>(row_ptr, edges, h, Xc, hsum);
    // ---- layer 3
    gemm_bias<HID, 16><<<gemm_grid, 256, 0, stream>>>(Xc, W3, b3, h);
    spmm_relu<3><<<spmm_grid, 256, 0, stream>>>(row_ptr, edges, h, Xc, hsum);

    // ---- pool + head
    find_starts<<<1, 128, 0, stream>>>(batch, starts);
    pool_kernel<<<N_GRAPHS, 256, 0, stream>>>(hsum, starts, pooled);
    head_kernel<<<N_GRAPHS, 64, 0, stream>>>(pooled, Wout, bout, out);
}

// Round 5
// 641.465 us; speedup vs baseline: 7.0114x; 1.1954x over previous
//
#include <hip/hip_runtime.h>
#include <hip/hip_bf16.h>
#include <math.h>

#define N_NODES   100000
#define N_EDGES   3200000
#define IN_DIM    128
#define HID       64
#define OUT_DIM   10
#define N_GRAPHS  64

// Coarse bucketing: bucket = row >> 7 (128 rows/bucket)
#define BUCKET_SHIFT 7
#define BUCKET_ROWS  128
#define NBUCKET ((N_NODES + BUCKET_ROWS - 1) >> BUCKET_SHIFT)     // 782
#define TILE_EDGES 8192                                           // 256 thr x 32
#define NTILES ((N_EDGES + TILE_EDGES - 1) / TILE_EDGES)          // 391
#define NH (NBUCKET * NTILES)                                     // 305,762
#define NSCAN1 ((NH + 1023) / 1024)                               // 299

typedef unsigned long long ull;
typedef unsigned short ushort;
typedef __attribute__((ext_vector_type(8))) short short8;   // 8 bf16 (4 VGPRs)
typedef __attribute__((ext_vector_type(4))) float f32x4;    // MFMA C/D

__device__ __forceinline__ ushort rne_bf16(float x) {
    unsigned u = __float_as_uint(x);
    return (ushort)((u + 0x7fffu + ((u >> 16) & 1u)) >> 16);
}

// ---------------------------------------------------------------- pass A
__global__ __launch_bounds__(256) void hist_pass(const int* __restrict__ rows,
                                                 int* __restrict__ hist) {
    __shared__ int h[NBUCKET];
    int tid = threadIdx.x, tile = blockIdx.x;
    for (int i = tid; i < NBUCKET; i += 256) h[i] = 0;
    __syncthreads();
    int base = tile * TILE_EDGES;
#pragma unroll
    for (int i = 0; i < 32; i++) {
        int e = base + i * 256 + tid;
        if (e < N_EDGES) atomicAdd(&h[rows[e] >> BUCKET_SHIFT], 1);
    }
    __syncthreads();
    for (int i = tid; i < NBUCKET; i += 256) hist[i * NTILES + tile] = h[i];
}

// ---------------------------------------------------------------- scan
__global__ __launch_bounds__(256) void scan_blocks(const int* __restrict__ in,
                                                   int* __restrict__ out,
                                                   int* __restrict__ blk, int n) {
    __shared__ int sdata[256];
    int t = threadIdx.x;
    int base = blockIdx.x * 1024 + t * 4;
    int v[4];
#pragma unroll
    for (int i = 0; i < 4; i++) {
        int idx = base + i;
        v[i] = (idx < n) ? in[idx] : 0;
    }
    int s = v[0] + v[1] + v[2] + v[3];
    sdata[t] = s;
    __syncthreads();
    for (int off = 1; off < 256; off <<= 1) {
        int x = (t >= off) ? sdata[t - off] : 0;
        __syncthreads();
        sdata[t] += x;
        __syncthreads();
    }
    int excl = sdata[t] - s;
#pragma unroll
    for (int i = 0; i < 4; i++) {
        int idx = base + i;
        if (idx < n) { out[idx] = excl; excl += v[i]; }
    }
    if (t == 255) blk[blockIdx.x] = sdata[255];
}

__global__ __launch_bounds__(256) void scan_add(int* __restrict__ data,
                                                const int* __restrict__ blk, int n) {
    int i = blockIdx.x * 256 + threadIdx.x;
    if (i < n) data[i] += blk[i >> 10];
}

// ---------------------------------------------------------------- pass B
__global__ __launch_bounds__(256) void scatter_pass(const int* __restrict__ rows,
                                                    const int* __restrict__ cols,
                                                    const float* __restrict__ vals,
                                                    const int* __restrict__ histScan,
                                                    ull* __restrict__ etmp) {
    __shared__ int cur[NBUCKET];
    int tid = threadIdx.x, tile = blockIdx.x;
    for (int i = tid; i < NBUCKET; i += 256) cur[i] = histScan[i * NTILES + tile];
    __syncthreads();
    int base = tile * TILE_EDGES;
#pragma unroll
    for (int i = 0; i < 32; i++) {
        int e = base + i * 256 + tid;
        if (e < N_EDGES) {
            int r = rows[e];
            int b = r >> BUCKET_SHIFT;
            int pos = atomicAdd(&cur[b], 1);      // LDS atomic, block-local
            unsigned hi = ((unsigned)(r & (BUCKET_ROWS - 1)) << 24) | (unsigned)cols[e];
            etmp[pos] = ((ull)hi << 32) | (ull)__float_as_uint(vals[e]);
        }
    }
}

// ---------------------------------------------------------------- pass C
__global__ __launch_bounds__(256) void bucket_sort(const int* __restrict__ histScan,
                                                   const ull* __restrict__ etmp,
                                                   ull* __restrict__ edges,
                                                   int* __restrict__ row_ptr) {
    __shared__ int rcnt[BUCKET_ROWS];
    __shared__ int roff[BUCKET_ROWS];
    __shared__ int rcur[BUCKET_ROWS];
    int b = blockIdx.x, t = threadIdx.x;
    int s = histScan[b * NTILES];
    int e = (b + 1 < NBUCKET) ? histScan[(b + 1) * NTILES] : N_EDGES;
    if (t < BUCKET_ROWS) rcnt[t] = 0;
    __syncthreads();
    for (int j = s + t; j < e; j += 256)
        atomicAdd(&rcnt[(int)(etmp[j] >> 56)], 1);
    __syncthreads();
    if (t < BUCKET_ROWS) roff[t] = rcnt[t];
    __syncthreads();
    for (int off = 1; off < BUCKET_ROWS; off <<= 1) {
        int x = (t >= off && t < BUCKET_ROWS) ? roff[t - off] : 0;
        __syncthreads();
        if (t < BUCKET_ROWS) roff[t] += x;
        __syncthreads();
    }
    if (t < BUCKET_ROWS) {
        int excl = roff[t] - rcnt[t];
        rcur[t] = s + excl;
        int grow = b * BUCKET_ROWS + t;
        if (grow < N_NODES) row_ptr[grow] = s + excl;
    }
    if (b == NBUCKET - 1 && t == 0) row_ptr[N_NODES] = N_EDGES;
    __syncthreads();
    for (int j = s + t; j < e; j += 256) {
        ull p = etmp[j];
        int rl = (int)(p >> 56);
        unsigned col = (unsigned)(p >> 32) & 0xFFFFFFu;
        int pos = atomicAdd(&rcur[rl], 1);        // LDS atomic
        edges[pos] = ((p & 0xFFFFFFFFull) << 32) | (ull)col;
    }
}

// ------------------------------------------------------------------- GEMM
// MFMA bf16: H[M,64] = X[M,K] @ W[64,K]^T + b, output bf16.
// Block = 4 waves x 16-row tiles (64 rows). Each wave: 4 n-subtiles x K/32
// k-steps of v_mfma_f32_16x16x32_bf16. X read EXACTLY ONCE (R4's 4-way
// channel split re-read X 4x -> 266 MB FETCH). W/bias are L1-resident.
// A[m=lane&15][k=quad*8+j]; B[k=quad*8+j][n=lane&15]; D col=lane&15,
// row=quad*4+reg (m89/m91-verified layouts).
template <int K, typename XT>
__global__ __launch_bounds__(256) void gemm_mfma(const XT* __restrict__ X,
                                                 const float* __restrict__ W,
                                                 const float* __restrict__ B,
                                                 ushort* __restrict__ H) {
    constexpr int KS = K / 32;
    int wave = threadIdx.x >> 6;
    int lane = threadIdx.x & 63;
    int quad = lane >> 4;
    int l16  = lane & 15;
    int rowBase = blockIdx.x * 64 + wave * 16;
    int arow = rowBase + l16;
    if (arow > N_NODES - 1) arow = N_NODES - 1;   // clamp OOB loads (stores guarded)

    short8 a[KS];
#pragma unroll
    for (int ks = 0; ks < KS; ks++) {
        int k = ks * 32 + quad * 8;
        if constexpr (sizeof(XT) == 2) {
            a[ks] = *reinterpret_cast<const short8*>(X + (size_t)arow * K + k);
        } else {
            const float4* src = reinterpret_cast<const float4*>(X + (size_t)arow * K + k);
            float4 t0 = src[0], t1 = src[1];
            union { short8 v; ushort u[8]; } cv;
            cv.u[0] = rne_bf16(t0.x); cv.u[1] = rne_bf16(t0.y);
            cv.u[2] = rne_bf16(t0.z); cv.u[3] = rne_bf16(t0.w);
            cv.u[4] = rne_bf16(t1.x); cv.u[5] = rne_bf16(t1.y);
            cv.u[6] = rne_bf16(t1.z); cv.u[7] = rne_bf16(t1.w);
            a[ks] = cv.v;
        }
    }

    f32x4 acc[4];
#pragma unroll
    for (int nt = 0; nt < 4; nt++) acc[nt] = 0.f;

#pragma unroll
    for (int nt = 0; nt < 4; nt++) {
        int brow = nt * 16 + l16;                 // W row = output channel n
#pragma unroll
        for (int ks = 0; ks < KS; ks++) {
            int k = ks * 32 + quad * 8;
            const float4* src = reinterpret_cast<const float4*>(W + brow * K + k);
            float4 t0 = src[0], t1 = src[1];
            union { short8 v; ushort u[8]; } cv;
            cv.u[0] = rne_bf16(t0.x); cv.u[1] = rne_bf16(t0.y);
            cv.u[2] = rne_bf16(t0.z); cv.u[3] = rne_bf16(t0.w);
            cv.u[4] = rne_bf16(t1.x); cv.u[5] = rne_bf16(t1.y);
            cv.u[6] = rne_bf16(t1.z); cv.u[7] = rne_bf16(t1.w);
            acc[nt] = __builtin_amdgcn_mfma_f32_16x16x32_bf16(a[ks], cv.v, acc[nt], 0, 0, 0);
        }
    }

#pragma unroll
    for (int nt = 0; nt < 4; nt++) {
        int n = nt * 16 + l16;
        float bv = B[n];
#pragma unroll
        for (int reg = 0; reg < 4; reg++) {
            int m = rowBase + quad * 4 + reg;
            if (m < N_NODES) H[(size_t)m * HID + n] = rne_bf16(acc[nt][reg] + bv);
        }
    }
}

// ------------------------------------------------------------------- SpMM
// Row-per-wave, lane = feature, bf16 gathers (128B/edge), 8-deep unroll.
// Xout written as bf16 (feeds the next MFMA gemm directly); Hsum fp32.
template <int MODE>
__global__ __launch_bounds__(256) void spmm_relu(const int* __restrict__ row_ptr,
                                                 const ull* __restrict__ edges,
                                                 const ushort* __restrict__ Hin,
                                                 ushort* __restrict__ Xout,
                                                 float* __restrict__ Hsum) {
    int wid  = (blockIdx.x * 256 + threadIdx.x) >> 6;
    int lane = threadIdx.x & 63;
    if (wid >= N_NODES) return;
    int r = __builtin_amdgcn_readfirstlane(wid);  // wave-uniform -> s_loads
    int start = row_ptr[r];
    int end   = row_ptr[r + 1];
    float acc = 0.f;
    int e = start;
    for (; e + 8 <= end; e += 8) {
        ull p[8];
#pragma unroll
        for (int i = 0; i < 8; i++) p[i] = edges[e + i];
        float h[8];
#pragma unroll
        for (int i = 0; i < 8; i++) {
            int c = (int)(unsigned)(p[i] & 0xFFFFFFFFull);
            h[i] = __uint_as_float((unsigned)Hin[c * HID + lane] << 16);
        }
#pragma unroll
        for (int i = 0; i < 8; i++) {
            float v = __uint_as_float((unsigned)(p[i] >> 32));
            acc += v * h[i];
        }
    }
    for (; e < end; e++) {
        ull p = edges[e];
        int c = (int)(unsigned)(p & 0xFFFFFFFFull);
        float v = __uint_as_float((unsigned)(p >> 32));
        acc += v * __uint_as_float((unsigned)Hin[c * HID + lane] << 16);
    }
    float val = fmaxf(acc, 0.f);
    int idx = r * HID + lane;
    if (MODE != 3) Xout[idx] = rne_bf16(val);
    if (MODE == 1) Hsum[idx] = val; else Hsum[idx] += val;
}

// ------------------------------------------------------------------- Pool
__global__ __launch_bounds__(128) void find_starts(const int* __restrict__ batch,
                                                   int* __restrict__ starts) {
    int g = threadIdx.x;
    if (g > N_GRAPHS) return;
    if (g == N_GRAPHS) { starts[g] = N_NODES; return; }
    int lo = 0, hi = N_NODES;
    while (lo < hi) {
        int mid = (lo + hi) >> 1;
        if (batch[mid] < g) lo = mid + 1; else hi = mid;
    }
    starts[g] = lo;
}

__global__ __launch_bounds__(256) void pool_kernel(const float* __restrict__ Hsum,
                                                   const int* __restrict__ starts,
                                                   float* __restrict__ pooled) {
    __shared__ float red[4][HID];
    int g = blockIdx.x;
    int lane = threadIdx.x & 63;
    int w = threadIdx.x >> 6;
    int s = starts[g], epos = starts[g + 1];
    float acc = 0.f;
    for (int n = s + w; n < epos; n += 4) acc += Hsum[(size_t)n * HID + lane];
    red[w][lane] = acc;
    __syncthreads();
    if (w == 0) {
        float tot = red[0][lane] + red[1][lane] + red[2][lane] + red[3][lane];
        int cntg = epos - s;
        float denom = 3.0f * (float)(cntg > 1 ? cntg : 1);
        pooled[g * HID + lane] = tot / denom;
    }
}

// ------------------------------------------------------------------- Head
__global__ __launch_bounds__(64) void head_kernel(const float* __restrict__ pooled,
                                                  const float* __restrict__ Wout,
                                                  const float* __restrict__ bout,
                                                  float* __restrict__ out) {
    int g = blockIdx.x;
    int t = threadIdx.x;
    __shared__ float pr[HID];
    __shared__ float lg[OUT_DIM];
    __shared__ float mx, sm;
    pr[t] = pooled[g * HID + t];
    __syncthreads();
    if (t < OUT_DIM) {
        float a = bout[t];
        for (int k = 0; k < HID; k++) a += pr[k] * Wout[t * HID + k];
        lg[t] = a;
    }
    __syncthreads();
    if (t == 0) {
        float m = lg[0];
        for (int j = 1; j < OUT_DIM; j++) m = fmaxf(m, lg[j]);
        float s = 0.f;
        for (int j = 0; j < OUT_DIM; j++) s += expf(lg[j] - m);
        mx = m; sm = s;
    }
    __syncthreads();
    if (t < OUT_DIM) out[g * OUT_DIM + t] = expf(lg[t] - mx) / sm;
}

// ---------------------------------------------------------------- launcher
extern "C" void kernel_launch(void* const* d_in, const int* in_sizes, int n_in,
                              void* d_out, int out_size, void* d_ws, size_t ws_size,
                              hipStream_t stream) {
    const float* X    = (const float*)d_in[0];
    const float* vals = (const float*)d_in[1];
    const float* W1   = (const float*)d_in[2];
    const float* b1   = (const float*)d_in[3];
    const float* W2   = (const float*)d_in[4];
    const float* b2   = (const float*)d_in[5];
    const float* W3   = (const float*)d_in[6];
    const float* b3   = (const float*)d_in[7];
    const float* Wout = (const float*)d_in[8];
    const float* bout = (const float*)d_in[9];
    const int*   rows = (const int*)d_in[10];
    const int*   cols = (const int*)d_in[11];
    const int*   batch= (const int*)d_in[12];
    float* out = (float*)d_out;

    char* p = (char*)d_ws;
    auto carve = [&](size_t bytes) {
        void* q = (void*)p;
        p += (bytes + 255) & ~(size_t)255;
        return q;
    };
    ushort* h     = (ushort*)carve((size_t)N_NODES * HID * 2);
    ushort* Xc    = (ushort*)carve((size_t)N_NODES * HID * 4);  // oversized: aliases etmp
    float* hsum   = (float*)carve((size_t)N_NODES * HID * 4);
    int*   hist   = (int*)  carve((size_t)NH * 4);
    int*   row_ptr= (int*)  carve((size_t)(N_NODES + 1) * 4);
    int*   blkA   = (int*)  carve(1024 * 4);
    int*   blkB   = (int*)  carve(1024 * 4);
    int*   starts = (int*)  carve((N_GRAPHS + 1) * 4);
    float* pooled = (float*)carve(N_GRAPHS * HID * 4);
    ull*   edges  = (ull*)  carve((size_t)N_EDGES * 8);
    // etmp aliases Xc: etmp dead before the first spmm writes Xc.
    ull*   etmp   = (ull*)Xc;
    (void)ws_size; (void)in_sizes; (void)n_in; (void)out_size;

    // ---- build: histogram -> scan -> bucket-grouped scatter -> local sort
    hist_pass<<<NTILES, 256, 0, stream>>>(rows, hist);
    scan_blocks<<<NSCAN1, 256, 0, stream>>>(hist, hist, blkA, NH);
    scan_blocks<<<1, 256, 0, stream>>>(blkA, blkA, blkB, NSCAN1);
    scan_add<<<(NH + 255) / 256, 256, 0, stream>>>(hist, blkA, NH);
    scatter_pass<<<NTILES, 256, 0, stream>>>(rows, cols, vals, hist, etmp);
    bucket_sort<<<NBUCKET, 256, 0, stream>>>(hist, etmp, edges, row_ptr);

    const int gemm_grid = (N_NODES + 63) / 64;   // 64 rows/block
    const int spmm_grid = (N_NODES + 3) / 4;

    // ---- layer 1
    gemm_mfma<IN_DIM, float><<<gemm_grid, 256, 0, stream>>>(X, W1, b1, h);
    spmm_relu<1><<<spmm_grid, 256, 0, stream>>>(row_ptr, edges, h, Xc, hsum);
    // ---- layer 2
    gemm_mfma<HID, ushort><<<gemm_grid, 256, 0, stream>>>(Xc, W2, b2, h);
    spmm_relu<2><<<spmm_grid, 256, 0, stream>>>(row_ptr, edges, h, Xc, hsum);
    // ---- layer 3
    gemm_mfma<HID, ushort><<<gemm_grid, 256, 0, stream>>>(Xc, W3, b3, h);
    spmm_relu<3><<<spmm_grid, 256, 0, stream>>>(row_ptr, edges, h, Xc, hsum);

    // ---- pool + head
    find_starts<<<1, 128, 0, stream>>>(batch, starts);
    pool_kernel<<<N_GRAPHS, 256, 0, stream>>>(hsum, starts, pooled);
    head_kernel<<<N_GRAPHS, 64, 0, stream>>>(pooled, Wout, bout, out);
}

// Round 6
// 539.836 us; speedup vs baseline: 8.3314x; 1.1883x over previous
//
#include <hip/hip_runtime.h>
#include <hip/hip_bf16.h>
#include <math.h>

#define N_NODES   100000
#define N_EDGES   3200000
#define IN_DIM    128
#define HID       64
#define OUT_DIM   10
#define N_GRAPHS  64

// Coarse bucketing: bucket = row >> 7 (128 rows/bucket)
#define BUCKET_SHIFT 7
#define BUCKET_ROWS  128
#define NBUCKET ((N_NODES + BUCKET_ROWS - 1) >> BUCKET_SHIFT)     // 782
#define TILE_EDGES 8192                                           // 256 thr x 32
#define NTILES ((N_EDGES + TILE_EDGES - 1) / TILE_EDGES)          // 391
#define NH (NBUCKET * NTILES)                                     // 305,762
#define NSCAN1 ((NH + 1023) / 1024)                               // 299

#define POOL_NODES 128   // nodes per pool block (4 waves x 32)

typedef unsigned long long ull;
typedef unsigned short ushort;
typedef __attribute__((ext_vector_type(8))) short short8;   // 8 bf16 (4 VGPRs)
typedef __attribute__((ext_vector_type(4))) float f32x4;    // MFMA C/D

__device__ __forceinline__ ushort rne_bf16(float x) {
    unsigned u = __float_as_uint(x);
    return (ushort)((u + 0x7fffu + ((u >> 16) & 1u)) >> 16);
}

// ---------------------------------------------------------------- pass A
__global__ __launch_bounds__(256) void hist_pass(const int* __restrict__ rows,
                                                 int* __restrict__ hist) {
    __shared__ int h[NBUCKET];
    int tid = threadIdx.x, tile = blockIdx.x;
    for (int i = tid; i < NBUCKET; i += 256) h[i] = 0;
    __syncthreads();
    int base = tile * TILE_EDGES;
#pragma unroll
    for (int i = 0; i < 32; i++) {
        int e = base + i * 256 + tid;
        if (e < N_EDGES) atomicAdd(&h[rows[e] >> BUCKET_SHIFT], 1);
    }
    __syncthreads();
    for (int i = tid; i < NBUCKET; i += 256) hist[i * NTILES + tile] = h[i];
}

// ---------------------------------------------------------------- scan
__global__ __launch_bounds__(256) void scan_blocks(const int* __restrict__ in,
                                                   int* __restrict__ out,
                                                   int* __restrict__ blk, int n) {
    __shared__ int sdata[256];
    int t = threadIdx.x;
    int base = blockIdx.x * 1024 + t * 4;
    int v[4];
#pragma unroll
    for (int i = 0; i < 4; i++) {
        int idx = base + i;
        v[i] = (idx < n) ? in[idx] : 0;
    }
    int s = v[0] + v[1] + v[2] + v[3];
    sdata[t] = s;
    __syncthreads();
    for (int off = 1; off < 256; off <<= 1) {
        int x = (t >= off) ? sdata[t - off] : 0;
        __syncthreads();
        sdata[t] += x;
        __syncthreads();
    }
    int excl = sdata[t] - s;
#pragma unroll
    for (int i = 0; i < 4; i++) {
        int idx = base + i;
        if (idx < n) { out[idx] = excl; excl += v[i]; }
    }
    if (t == 255) blk[blockIdx.x] = sdata[255];
}

__global__ __launch_bounds__(256) void scan_add(int* __restrict__ data,
                                                const int* __restrict__ blk, int n) {
    int i = blockIdx.x * 256 + threadIdx.x;
    if (i < n) data[i] += blk[i >> 10];
}

// ---------------------------------------------------------------- pass B
__global__ __launch_bounds__(256) void scatter_pass(const int* __restrict__ rows,
                                                    const int* __restrict__ cols,
                                                    const float* __restrict__ vals,
                                                    const int* __restrict__ histScan,
                                                    ull* __restrict__ etmp) {
    __shared__ int cur[NBUCKET];
    int tid = threadIdx.x, tile = blockIdx.x;
    for (int i = tid; i < NBUCKET; i += 256) cur[i] = histScan[i * NTILES + tile];
    __syncthreads();
    int base = tile * TILE_EDGES;
#pragma unroll
    for (int i = 0; i < 32; i++) {
        int e = base + i * 256 + tid;
        if (e < N_EDGES) {
            int r = rows[e];
            int b = r >> BUCKET_SHIFT;
            int pos = atomicAdd(&cur[b], 1);      // LDS atomic, block-local
            unsigned hi = ((unsigned)(r & (BUCKET_ROWS - 1)) << 24) | (unsigned)cols[e];
            etmp[pos] = ((ull)hi << 32) | (ull)__float_as_uint(vals[e]);
        }
    }
}

// ---------------------------------------------------------------- pass C
__global__ __launch_bounds__(256) void bucket_sort(const int* __restrict__ histScan,
                                                   const ull* __restrict__ etmp,
                                                   ull* __restrict__ edges,
                                                   int* __restrict__ row_ptr) {
    __shared__ int rcnt[BUCKET_ROWS];
    __shared__ int roff[BUCKET_ROWS];
    __shared__ int rcur[BUCKET_ROWS];
    int b = blockIdx.x, t = threadIdx.x;
    int s = histScan[b * NTILES];
    int e = (b + 1 < NBUCKET) ? histScan[(b + 1) * NTILES] : N_EDGES;
    if (t < BUCKET_ROWS) rcnt[t] = 0;
    __syncthreads();
    for (int j = s + t; j < e; j += 256)
        atomicAdd(&rcnt[(int)(etmp[j] >> 56)], 1);
    __syncthreads();
    if (t < BUCKET_ROWS) roff[t] = rcnt[t];
    __syncthreads();
    for (int off = 1; off < BUCKET_ROWS; off <<= 1) {
        int x = (t >= off && t < BUCKET_ROWS) ? roff[t - off] : 0;
        __syncthreads();
        if (t < BUCKET_ROWS) roff[t] += x;
        __syncthreads();
    }
    if (t < BUCKET_ROWS) {
        int excl = roff[t] - rcnt[t];
        rcur[t] = s + excl;
        int grow = b * BUCKET_ROWS + t;
        if (grow < N_NODES) row_ptr[grow] = s + excl;
    }
    if (b == NBUCKET - 1 && t == 0) row_ptr[N_NODES] = N_EDGES;
    __syncthreads();
    for (int j = s + t; j < e; j += 256) {
        ull p = etmp[j];
        int rl = (int)(p >> 56);
        unsigned col = (unsigned)(p >> 32) & 0xFFFFFFu;
        int pos = atomicAdd(&rcur[rl], 1);        // LDS atomic
        edges[pos] = ((p & 0xFFFFFFFFull) << 32) | (ull)col;
    }
}

// ------------------------------------------------------------------- GEMM
// MFMA bf16: H[M,64] = X[M,K] @ W[64,K]^T + b, output bf16. X read once.
template <int K, typename XT>
__global__ __launch_bounds__(256) void gemm_mfma(const XT* __restrict__ X,
                                                 const float* __restrict__ W,
                                                 const float* __restrict__ B,
                                                 ushort* __restrict__ H) {
    constexpr int KS = K / 32;
    int wave = threadIdx.x >> 6;
    int lane = threadIdx.x & 63;
    int quad = lane >> 4;
    int l16  = lane & 15;
    int rowBase = blockIdx.x * 64 + wave * 16;
    int arow = rowBase + l16;
    if (arow > N_NODES - 1) arow = N_NODES - 1;   // clamp OOB loads (stores guarded)

    short8 a[KS];
#pragma unroll
    for (int ks = 0; ks < KS; ks++) {
        int k = ks * 32 + quad * 8;
        if constexpr (sizeof(XT) == 2) {
            a[ks] = *reinterpret_cast<const short8*>(X + (size_t)arow * K + k);
        } else {
            const float4* src = reinterpret_cast<const float4*>(X + (size_t)arow * K + k);
            float4 t0 = src[0], t1 = src[1];
            union { short8 v; ushort u[8]; } cv;
            cv.u[0] = rne_bf16(t0.x); cv.u[1] = rne_bf16(t0.y);
            cv.u[2] = rne_bf16(t0.z); cv.u[3] = rne_bf16(t0.w);
            cv.u[4] = rne_bf16(t1.x); cv.u[5] = rne_bf16(t1.y);
            cv.u[6] = rne_bf16(t1.z); cv.u[7] = rne_bf16(t1.w);
            a[ks] = cv.v;
        }
    }

    f32x4 acc[4];
#pragma unroll
    for (int nt = 0; nt < 4; nt++) acc[nt] = 0.f;

#pragma unroll
    for (int nt = 0; nt < 4; nt++) {
        int brow = nt * 16 + l16;                 // W row = output channel n
#pragma unroll
        for (int ks = 0; ks < KS; ks++) {
            int k = ks * 32 + quad * 8;
            const float4* src = reinterpret_cast<const float4*>(W + brow * K + k);
            float4 t0 = src[0], t1 = src[1];
            union { short8 v; ushort u[8]; } cv;
            cv.u[0] = rne_bf16(t0.x); cv.u[1] = rne_bf16(t0.y);
            cv.u[2] = rne_bf16(t0.z); cv.u[3] = rne_bf16(t0.w);
            cv.u[4] = rne_bf16(t1.x); cv.u[5] = rne_bf16(t1.y);
            cv.u[6] = rne_bf16(t1.z); cv.u[7] = rne_bf16(t1.w);
            acc[nt] = __builtin_amdgcn_mfma_f32_16x16x32_bf16(a[ks], cv.v, acc[nt], 0, 0, 0);
        }
    }

#pragma unroll
    for (int nt = 0; nt < 4; nt++) {
        int n = nt * 16 + l16;
        float bv = B[n];
#pragma unroll
        for (int reg = 0; reg < 4; reg++) {
            int m = rowBase + quad * 4 + reg;
            if (m < N_NODES) H[(size_t)m * HID + n] = rne_bf16(acc[nt][reg] + bv);
        }
    }
}

// ------------------------------------------------------------------- SpMM
// Row-per-wave, lane = feature, bf16 gathers (128B/edge), 16-deep unroll
// (avg row = 32 edges; deeper unroll = more outstanding gathers if
// latency-bound; flat if L3-BW-bound).
template <int MODE>
__global__ __launch_bounds__(256) void spmm_relu(const int* __restrict__ row_ptr,
                                                 const ull* __restrict__ edges,
                                                 const ushort* __restrict__ Hin,
                                                 ushort* __restrict__ Xout,
                                                 float* __restrict__ Hsum) {
    int wid  = (blockIdx.x * 256 + threadIdx.x) >> 6;
    int lane = threadIdx.x & 63;
    if (wid >= N_NODES) return;
    int r = __builtin_amdgcn_readfirstlane(wid);  // wave-uniform -> s_loads
    int start = row_ptr[r];
    int end   = row_ptr[r + 1];
    float acc = 0.f;
    int e = start;
    for (; e + 16 <= end; e += 16) {
        ull p[16];
#pragma unroll
        for (int i = 0; i < 16; i++) p[i] = edges[e + i];
        float h[16];
#pragma unroll
        for (int i = 0; i < 16; i++) {
            int c = (int)(unsigned)(p[i] & 0xFFFFFFFFull);
            h[i] = __uint_as_float((unsigned)Hin[c * HID + lane] << 16);
        }
#pragma unroll
        for (int i = 0; i < 16; i++) {
            float v = __uint_as_float((unsigned)(p[i] >> 32));
            acc += v * h[i];
        }
    }
    for (; e + 4 <= end; e += 4) {
        ull p[4];
#pragma unroll
        for (int i = 0; i < 4; i++) p[i] = edges[e + i];
#pragma unroll
        for (int i = 0; i < 4; i++) {
            int c = (int)(unsigned)(p[i] & 0xFFFFFFFFull);
            float v = __uint_as_float((unsigned)(p[i] >> 32));
            acc += v * __uint_as_float((unsigned)Hin[c * HID + lane] << 16);
        }
    }
    for (; e < end; e++) {
        ull p = edges[e];
        int c = (int)(unsigned)(p & 0xFFFFFFFFull);
        float v = __uint_as_float((unsigned)(p >> 32));
        acc += v * __uint_as_float((unsigned)Hin[c * HID + lane] << 16);
    }
    float val = fmaxf(acc, 0.f);
    int idx = r * HID + lane;
    if (MODE != 3) Xout[idx] = rne_bf16(val);
    if (MODE == 1) Hsum[idx] = val; else Hsum[idx] += val;
}

// ------------------------------------------------------------------- Pool
__global__ __launch_bounds__(128) void find_starts(const int* __restrict__ batch,
                                                   int* __restrict__ starts) {
    int g = threadIdx.x;
    if (g > N_GRAPHS) return;
    if (g == N_GRAPHS) { starts[g] = N_NODES; return; }
    int lo = 0, hi = N_NODES;
    while (lo < hi) {
        int mid = (lo + hi) >> 1;
        if (batch[mid] < g) lo = mid + 1; else hi = mid;
    }
    starts[g] = lo;
}

// Parallel segmented pool: 782 blocks x 4 waves, each wave sums a 32-node
// sub-chunk (lane = feature). batch sorted -> few segments per sub-chunk;
// one global atomicAdd per segment into sums[64][64] (16 KB, zeroed).
__global__ __launch_bounds__(256) void pool_partial(const float* __restrict__ Hsum,
                                                    const int* __restrict__ batch,
                                                    float* __restrict__ sums) {
    int lane = threadIdx.x & 63;
    int w = threadIdx.x >> 6;
    int n0 = blockIdx.x * POOL_NODES + w * (POOL_NODES / 4);
    if (n0 >= N_NODES) return;
    int n1 = n0 + POOL_NODES / 4;
    if (n1 > N_NODES) n1 = N_NODES;
    int g_cur = __builtin_amdgcn_readfirstlane(batch[n0]);
    float acc = 0.f;
    for (int n = n0; n < n1; n++) {
        int g = __builtin_amdgcn_readfirstlane(batch[n]);
        if (g != g_cur) {
            atomicAdd(&sums[g_cur * HID + lane], acc);
            acc = 0.f; g_cur = g;
        }
        acc += Hsum[(size_t)n * HID + lane];
    }
    atomicAdd(&sums[g_cur * HID + lane], acc);
}

// ------------------------------------------------------------------- Head
__global__ __launch_bounds__(64) void head_kernel(const float* __restrict__ sums,
                                                  const int* __restrict__ starts,
                                                  const float* __restrict__ Wout,
                                                  const float* __restrict__ bout,
                                                  float* __restrict__ out) {
    int g = blockIdx.x;
    int t = threadIdx.x;
    __shared__ float pr[HID];
    __shared__ float lg[OUT_DIM];
    __shared__ float mx, sm;
    int cnt = starts[g + 1] - starts[g];
    float denom = 3.0f * (float)(cnt > 1 ? cnt : 1);
    pr[t] = sums[g * HID + t] / denom;
    __syncthreads();
    if (t < OUT_DIM) {
        float a = bout[t];
        for (int k = 0; k < HID; k++) a += pr[k] * Wout[t * HID + k];
        lg[t] = a;
    }
    __syncthreads();
    if (t == 0) {
        float m = lg[0];
        for (int j = 1; j < OUT_DIM; j++) m = fmaxf(m, lg[j]);
        float s = 0.f;
        for (int j = 0; j < OUT_DIM; j++) s += expf(lg[j] - m);
        mx = m; sm = s;
    }
    __syncthreads();
    if (t < OUT_DIM) out[g * OUT_DIM + t] = expf(lg[t] - mx) / sm;
}

// ---------------------------------------------------------------- launcher
extern "C" void kernel_launch(void* const* d_in, const int* in_sizes, int n_in,
                              void* d_out, int out_size, void* d_ws, size_t ws_size,
                              hipStream_t stream) {
    const float* X    = (const float*)d_in[0];
    const float* vals = (const float*)d_in[1];
    const float* W1   = (const float*)d_in[2];
    const float* b1   = (const float*)d_in[3];
    const float* W2   = (const float*)d_in[4];
    const float* b2   = (const float*)d_in[5];
    const float* W3   = (const float*)d_in[6];
    const float* b3   = (const float*)d_in[7];
    const float* Wout = (const float*)d_in[8];
    const float* bout = (const float*)d_in[9];
    const int*   rows = (const int*)d_in[10];
    const int*   cols = (const int*)d_in[11];
    const int*   batch= (const int*)d_in[12];
    float* out = (float*)d_out;

    char* p = (char*)d_ws;
    auto carve = [&](size_t bytes) {
        void* q = (void*)p;
        p += (bytes + 255) & ~(size_t)255;
        return q;
    };
    ushort* h     = (ushort*)carve((size_t)N_NODES * HID * 2);
    ushort* Xc    = (ushort*)carve((size_t)N_NODES * HID * 4);  // oversized: aliases etmp
    float* hsum   = (float*)carve((size_t)N_NODES * HID * 4);
    int*   hist   = (int*)  carve((size_t)NH * 4);
    int*   row_ptr= (int*)  carve((size_t)(N_NODES + 1) * 4);
    int*   blkA   = (int*)  carve(1024 * 4);
    int*   blkB   = (int*)  carve(1024 * 4);
    int*   starts = (int*)  carve((N_GRAPHS + 1) * 4);
    float* sums   = (float*)carve(N_GRAPHS * HID * 4);
    ull*   edges  = (ull*)  carve((size_t)N_EDGES * 8);
    // etmp aliases Xc: etmp dead before the first spmm writes Xc.
    ull*   etmp   = (ull*)Xc;
    (void)ws_size; (void)in_sizes; (void)n_in; (void)out_size;

    // ---- build: histogram -> scan -> bucket-grouped scatter -> local sort
    hist_pass<<<NTILES, 256, 0, stream>>>(rows, hist);
    scan_blocks<<<NSCAN1, 256, 0, stream>>>(hist, hist, blkA, NH);
    scan_blocks<<<1, 256, 0, stream>>>(blkA, blkA, blkB, NSCAN1);
    scan_add<<<(NH + 255) / 256, 256, 0, stream>>>(hist, blkA, NH);
    scatter_pass<<<NTILES, 256, 0, stream>>>(rows, cols, vals, hist, etmp);
    bucket_sort<<<NBUCKET, 256, 0, stream>>>(hist, etmp, edges, row_ptr);

    const int gemm_grid = (N_NODES + 63) / 64;   // 64 rows/block
    const int spmm_grid = (N_NODES + 3) / 4;

    // ---- layer 1
    gemm_mfma<IN_DIM, float><<<gemm_grid, 256, 0, stream>>>(X, W1, b1, h);
    spmm_relu<1><<<spmm_grid, 256, 0, stream>>>(row_ptr, edges, h, Xc, hsum);
    // ---- layer 2
    gemm_mfma<HID, ushort><<<gemm_grid, 256, 0, stream>>>(Xc, W2, b2, h);
    spmm_relu<2><<<spmm_grid, 256, 0, stream>>>(row_ptr, edges, h, Xc, hsum);
    // ---- layer 3
    gemm_mfma<HID, ushort><<<gemm_grid, 256, 0, stream>>>(Xc, W3, b3, h);
    spmm_relu<3><<<spmm_grid, 256, 0, stream>>>(row_ptr, edges, h, Xc, hsum);

    // ---- pool + head
    hipMemsetAsync(sums, 0, N_GRAPHS * HID * 4, stream);
    find_starts<<<1, 128, 0, stream>>>(batch, starts);
    pool_partial<<<(N_NODES + POOL_NODES - 1) / POOL_NODES, 256, 0, stream>>>(hsum, batch, sums);
    head_kernel<<<N_GRAPHS, 64, 0, stream>>>(sums, starts, Wout, bout, out);
}

// Round 7
// 516.460 us; speedup vs baseline: 8.7085x; 1.0453x over previous
//
#include <hip/hip_runtime.h>
#include <hip/hip_bf16.h>
#include <math.h>

#define N_NODES   100000
#define N_EDGES   3200000
#define IN_DIM    128
#define HID       64
#define OUT_DIM   10
#define N_GRAPHS  64

// Radix geometry: bucket = row >> 8 (256 rows/bucket), tile = 4096 edges.
#define BUCKET_SHIFT 8
#define BUCKET_ROWS  256
#define NBUCKET ((N_NODES + BUCKET_ROWS - 1) >> BUCKET_SHIFT)     // 391
#define TILE_EDGES 4096                                           // 256 thr x 16
#define NTILES ((N_EDGES + TILE_EDGES - 1) / TILE_EDGES)          // 782
#define NH (NBUCKET * NTILES)                                     // 305,762
#define NSCAN1 ((NH + 1023) / 1024)                               // 299

typedef unsigned long long ull;
typedef unsigned short ushort;
typedef __attribute__((ext_vector_type(8))) short short8;   // 8 bf16 (4 VGPRs)
typedef __attribute__((ext_vector_type(4))) float f32x4;    // MFMA C/D

__device__ __forceinline__ ushort rne_bf16(float x) {
    unsigned u = __float_as_uint(x);
    return (ushort)((u + 0x7fffu + ((u >> 16) & 1u)) >> 16);
}
__device__ __forceinline__ float bf2f(ushort u) {
    return __uint_as_float((unsigned)u << 16);
}

// ---------------------------------------------------------------- pass A
// Per-tile LDS histogram; write histT[tile][bucket] (COALESCED — R6's
// [bucket][tile] layout cost ~20 MB of strided line traffic).
__global__ __launch_bounds__(256) void hist_pass(const int* __restrict__ rows,
                                                 int* __restrict__ histT) {
    __shared__ int h[NBUCKET];
    int tid = threadIdx.x, tile = blockIdx.x;
    for (int i = tid; i < NBUCKET; i += 256) h[i] = 0;
    __syncthreads();
    int base = tile * TILE_EDGES;
#pragma unroll
    for (int i = 0; i < 16; i++) {
        int e = base + i * 256 + tid;
        if (e < N_EDGES) atomicAdd(&h[rows[e] >> BUCKET_SHIFT], 1);
    }
    __syncthreads();
    for (int i = tid; i < NBUCKET; i += 256) histT[tile * NBUCKET + i] = h[i];
}

// ---------------------------------------------------------------- transpose
// in[R][C] -> out[C][R], 32x32 LDS tiles, fully coalesced both sides.
__global__ __launch_bounds__(1024) void transpose_int(const int* __restrict__ in,
                                                      int* __restrict__ out,
                                                      int R, int C) {
    __shared__ int tile[32][33];
    int tx = threadIdx.x, ty = threadIdx.y;
    int r = blockIdx.y * 32 + ty, c = blockIdx.x * 32 + tx;
    if (r < R && c < C) tile[ty][tx] = in[r * C + c];
    __syncthreads();
    int rr = blockIdx.y * 32 + tx, cc = blockIdx.x * 32 + ty;
    if (cc < C && rr < R) out[cc * R + rr] = tile[tx][ty];
}

// ---------------------------------------------------------------- scan
__global__ __launch_bounds__(256) void scan_blocks(const int* __restrict__ in,
                                                   int* __restrict__ out,
                                                   int* __restrict__ blk, int n) {
    __shared__ int sdata[256];
    int t = threadIdx.x;
    int base = blockIdx.x * 1024 + t * 4;
    int v[4];
#pragma unroll
    for (int i = 0; i < 4; i++) {
        int idx = base + i;
        v[i] = (idx < n) ? in[idx] : 0;
    }
    int s = v[0] + v[1] + v[2] + v[3];
    sdata[t] = s;
    __syncthreads();
    for (int off = 1; off < 256; off <<= 1) {
        int x = (t >= off) ? sdata[t - off] : 0;
        __syncthreads();
        sdata[t] += x;
        __syncthreads();
    }
    int excl = sdata[t] - s;
#pragma unroll
    for (int i = 0; i < 4; i++) {
        int idx = base + i;
        if (idx < n) { out[idx] = excl; excl += v[i]; }
    }
    if (t == 255) blk[blockIdx.x] = sdata[255];
}

__global__ __launch_bounds__(256) void scan_add(int* __restrict__ data,
                                                const int* __restrict__ blk, int n) {
    int i = blockIdx.x * 256 + threadIdx.x;
    if (i < n) data[i] += blk[i >> 10];
}

// ---------------------------------------------------------------- pass B
// Re-read edges; LDS cursors from cursorT[tile][bucket] (coalesced); write
// bucket-grouped packed records (rowLocal<<56 | col<<32 | val). No global
// atomics; ~21-edge (168 B) contiguous runs per tile-bucket.
__global__ __launch_bounds__(256) void scatter_pass(const int* __restrict__ rows,
                                                    const int* __restrict__ cols,
                                                    const float* __restrict__ vals,
                                                    const int* __restrict__ cursorT,
                                                    ull* __restrict__ etmp) {
    __shared__ int cur[NBUCKET];
    int tid = threadIdx.x, tile = blockIdx.x;
    for (int i = tid; i < NBUCKET; i += 256) cur[i] = cursorT[tile * NBUCKET + i];
    __syncthreads();
    int base = tile * TILE_EDGES;
#pragma unroll
    for (int i = 0; i < 16; i++) {
        int e = base + i * 256 + tid;
        if (e < N_EDGES) {
            int r = rows[e];
            int b = r >> BUCKET_SHIFT;
            int pos = atomicAdd(&cur[b], 1);      // LDS atomic, block-local
            unsigned hi = ((unsigned)(r & (BUCKET_ROWS - 1)) << 24) | (unsigned)cols[e];
            etmp[pos] = ((ull)hi << 32) | (ull)__float_as_uint(vals[e]);
        }
    }
}

// ---------------------------------------------------------------- pass C
// One 512-thr block per bucket: counting-sort ~8192 contiguous edges by
// local row, emit exact row_ptr + final packed edges (val<<32 | col).
__global__ __launch_bounds__(512) void bucket_sort(const int* __restrict__ histL,
                                                   const ull* __restrict__ etmp,
                                                   ull* __restrict__ edges,
                                                   int* __restrict__ row_ptr) {
    __shared__ int rcnt[BUCKET_ROWS];
    __shared__ int roff[BUCKET_ROWS];
    __shared__ int rcur[BUCKET_ROWS];
    int b = blockIdx.x, t = threadIdx.x;
    int s = histL[b * NTILES];
    int e = (b + 1 < NBUCKET) ? histL[(b + 1) * NTILES] : N_EDGES;
    if (t < BUCKET_ROWS) rcnt[t] = 0;
    __syncthreads();
    for (int j = s + t; j < e; j += 512)
        atomicAdd(&rcnt[(int)(etmp[j] >> 56)], 1);
    __syncthreads();
    if (t < BUCKET_ROWS) roff[t] = rcnt[t];
    __syncthreads();
    for (int off = 1; off < BUCKET_ROWS; off <<= 1) {
        int x = (t >= off && t < BUCKET_ROWS) ? roff[t - off] : 0;
        __syncthreads();
        if (t < BUCKET_ROWS) roff[t] += x;
        __syncthreads();
    }
    if (t < BUCKET_ROWS) {
        int excl = roff[t] - rcnt[t];
        rcur[t] = s + excl;
        int grow = b * BUCKET_ROWS + t;
        if (grow < N_NODES) row_ptr[grow] = s + excl;
    }
    if (b == NBUCKET - 1 && t == 0) row_ptr[N_NODES] = N_EDGES;
    __syncthreads();
    for (int j = s + t; j < e; j += 512) {
        ull p = etmp[j];
        int rl = (int)(p >> 56);
        unsigned col = (unsigned)(p >> 32) & 0xFFFFFFu;
        int pos = atomicAdd(&rcur[rl], 1);        // LDS atomic
        edges[pos] = ((p & 0xFFFFFFFFull) << 32) | (ull)col;
    }
}

// ------------------------------------------------------------------- GEMM
// MFMA bf16: H[M,64] = X[M,K] @ W[64,K]^T + b, output bf16. X read once.
template <int K, typename XT>
__global__ __launch_bounds__(256) void gemm_mfma(const XT* __restrict__ X,
                                                 const float* __restrict__ W,
                                                 const float* __restrict__ B,
                                                 ushort* __restrict__ H) {
    constexpr int KS = K / 32;
    int wave = threadIdx.x >> 6;
    int lane = threadIdx.x & 63;
    int quad = lane >> 4;
    int l16  = lane & 15;
    int rowBase = blockIdx.x * 64 + wave * 16;
    int arow = rowBase + l16;
    if (arow > N_NODES - 1) arow = N_NODES - 1;   // clamp OOB loads (stores guarded)

    short8 a[KS];
#pragma unroll
    for (int ks = 0; ks < KS; ks++) {
        int k = ks * 32 + quad * 8;
        if constexpr (sizeof(XT) == 2) {
            a[ks] = *reinterpret_cast<const short8*>(X + (size_t)arow * K + k);
        } else {
            const float4* src = reinterpret_cast<const float4*>(X + (size_t)arow * K + k);
            float4 t0 = src[0], t1 = src[1];
            union { short8 v; ushort u[8]; } cv;
            cv.u[0] = rne_bf16(t0.x); cv.u[1] = rne_bf16(t0.y);
            cv.u[2] = rne_bf16(t0.z); cv.u[3] = rne_bf16(t0.w);
            cv.u[4] = rne_bf16(t1.x); cv.u[5] = rne_bf16(t1.y);
            cv.u[6] = rne_bf16(t1.z); cv.u[7] = rne_bf16(t1.w);
            a[ks] = cv.v;
        }
    }

    f32x4 acc[4];
#pragma unroll
    for (int nt = 0; nt < 4; nt++) acc[nt] = 0.f;

#pragma unroll
    for (int nt = 0; nt < 4; nt++) {
        int brow = nt * 16 + l16;                 // W row = output channel n
#pragma unroll
        for (int ks = 0; ks < KS; ks++) {
            int k = ks * 32 + quad * 8;
            const float4* src = reinterpret_cast<const float4*>(W + brow * K + k);
            float4 t0 = src[0], t1 = src[1];
            union { short8 v; ushort u[8]; } cv;
            cv.u[0] = rne_bf16(t0.x); cv.u[1] = rne_bf16(t0.y);
            cv.u[2] = rne_bf16(t0.z); cv.u[3] = rne_bf16(t0.w);
            cv.u[4] = rne_bf16(t1.x); cv.u[5] = rne_bf16(t1.y);
            cv.u[6] = rne_bf16(t1.z); cv.u[7] = rne_bf16(t1.w);
            acc[nt] = __builtin_amdgcn_mfma_f32_16x16x32_bf16(a[ks], cv.v, acc[nt], 0, 0, 0);
        }
    }

#pragma unroll
    for (int nt = 0; nt < 4; nt++) {
        int n = nt * 16 + l16;
        float bv = B[n];
#pragma unroll
        for (int reg = 0; reg < 4; reg++) {
            int m = rowBase + quad * 4 + reg;
            if (m < N_NODES) H[(size_t)m * HID + n] = rne_bf16(acc[nt][reg] + bv);
        }
    }
}

// ------------------------------------------------------------------- SpMM
// Row-per-wave, lane = feature, bf16 gathers (128B/edge), 16-deep unroll.
// Writes ONLY bf16 Xout (Hsum eliminated via pooling linearity).
__global__ __launch_bounds__(256) void spmm_relu(const int* __restrict__ row_ptr,
                                                 const ull* __restrict__ edges,
                                                 const ushort* __restrict__ Hin,
                                                 ushort* __restrict__ Xout) {
    int wid  = (blockIdx.x * 256 + threadIdx.x) >> 6;
    int lane = threadIdx.x & 63;
    if (wid >= N_NODES) return;
    int r = __builtin_amdgcn_readfirstlane(wid);  // wave-uniform -> s_loads
    int start = row_ptr[r];
    int end   = row_ptr[r + 1];
    float acc = 0.f;
    int e = start;
    for (; e + 16 <= end; e += 16) {
        ull p[16];
#pragma unroll
        for (int i = 0; i < 16; i++) p[i] = edges[e + i];
        float h[16];
#pragma unroll
        for (int i = 0; i < 16; i++) {
            int c = (int)(unsigned)(p[i] & 0xFFFFFFFFull);
            h[i] = bf2f(Hin[c * HID + lane]);
        }
#pragma unroll
        for (int i = 0; i < 16; i++) {
            float v = __uint_as_float((unsigned)(p[i] >> 32));
            acc += v * h[i];
        }
    }
    for (; e + 4 <= end; e += 4) {
        ull p[4];
#pragma unroll
        for (int i = 0; i < 4; i++) p[i] = edges[e + i];
#pragma unroll
        for (int i = 0; i < 4; i++) {
            int c = (int)(unsigned)(p[i] & 0xFFFFFFFFull);
            float v = __uint_as_float((unsigned)(p[i] >> 32));
            acc += v * bf2f(Hin[c * HID + lane]);
        }
    }
    for (; e < end; e++) {
        ull p = edges[e];
        int c = (int)(unsigned)(p & 0xFFFFFFFFull);
        float v = __uint_as_float((unsigned)(p >> 32));
        acc += v * bf2f(Hin[c * HID + lane]);
    }
    Xout[r * HID + lane] = rne_bf16(fmaxf(acc, 0.f));
}

// ------------------------------------------------------------------- Pool
__global__ __launch_bounds__(128) void find_starts(const int* __restrict__ batch,
                                                   int* __restrict__ starts) {
    int g = threadIdx.x;
    if (g > N_GRAPHS) return;
    if (g == N_GRAPHS) { starts[g] = N_NODES; return; }
    int lo = 0, hi = N_NODES;
    while (lo < hi) {
        int mid = (lo + hi) >> 1;
        if (batch[mid] < g) lo = mid + 1; else hi = mid;
    }
    starts[g] = lo;
}

// Segmented pool over X1+X2+X3 (bf16): 782 blocks x 4 waves x 32 nodes,
// lane = feature; batch sorted -> one atomicAdd per segment per wave.
__global__ __launch_bounds__(256) void pool_fused(const ushort* __restrict__ X1,
                                                  const ushort* __restrict__ X2,
                                                  const ushort* __restrict__ X3,
                                                  const int* __restrict__ batch,
                                                  float* __restrict__ sums) {
    int lane = threadIdx.x & 63;
    int w = threadIdx.x >> 6;
    int n0 = blockIdx.x * 128 + w * 32;
    if (n0 >= N_NODES) return;
    int n1 = n0 + 32;
    if (n1 > N_NODES) n1 = N_NODES;
    int g_cur = __builtin_amdgcn_readfirstlane(batch[n0]);
    float acc = 0.f;
    for (int n = n0; n < n1; n++) {
        int g = __builtin_amdgcn_readfirstlane(batch[n]);
        if (g != g_cur) {
            atomicAdd(&sums[g_cur * HID + lane], acc);
            acc = 0.f; g_cur = g;
        }
        size_t base = (size_t)n * HID + lane;
        acc += bf2f(X1[base]) + bf2f(X2[base]) + bf2f(X3[base]);
    }
    atomicAdd(&sums[g_cur * HID + lane], acc);
}

// ------------------------------------------------------------------- Head
__global__ __launch_bounds__(64) void head_kernel(const float* __restrict__ sums,
                                                  const int* __restrict__ starts,
                                                  const float* __restrict__ Wout,
                                                  const float* __restrict__ bout,
                                                  float* __restrict__ out) {
    int g = blockIdx.x;
    int t = threadIdx.x;
    __shared__ float pr[HID];
    __shared__ float lg[OUT_DIM];
    __shared__ float mx, sm;
    int cnt = starts[g + 1] - starts[g];
    float denom = 3.0f * (float)(cnt > 1 ? cnt : 1);
    pr[t] = sums[g * HID + t] / denom;
    __syncthreads();
    if (t < OUT_DIM) {
        float a = bout[t];
        for (int k = 0; k < HID; k++) a += pr[k] * Wout[t * HID + k];
        lg[t] = a;
    }
    __syncthreads();
    if (t == 0) {
        float m = lg[0];
        for (int j = 1; j < OUT_DIM; j++) m = fmaxf(m, lg[j]);
        float s = 0.f;
        for (int j = 0; j < OUT_DIM; j++) s += expf(lg[j] - m);
        mx = m; sm = s;
    }
    __syncthreads();
    if (t < OUT_DIM) out[g * OUT_DIM + t] = expf(lg[t] - mx) / sm;
}

// ---------------------------------------------------------------- launcher
extern "C" void kernel_launch(void* const* d_in, const int* in_sizes, int n_in,
                              void* d_out, int out_size, void* d_ws, size_t ws_size,
                              hipStream_t stream) {
    const float* X    = (const float*)d_in[0];
    const float* vals = (const float*)d_in[1];
    const float* W1   = (const float*)d_in[2];
    const float* b1   = (const float*)d_in[3];
    const float* W2   = (const float*)d_in[4];
    const float* b2   = (const float*)d_in[5];
    const float* W3   = (const float*)d_in[6];
    const float* b3   = (const float*)d_in[7];
    const float* Wout = (const float*)d_in[8];
    const float* bout = (const float*)d_in[9];
    const int*   rows = (const int*)d_in[10];
    const int*   cols = (const int*)d_in[11];
    const int*   batch= (const int*)d_in[12];
    float* out = (float*)d_out;

    char* p = (char*)d_ws;
    auto carve = [&](size_t bytes) {
        void* q = (void*)p;
        p += (bytes + 255) & ~(size_t)255;
        return q;
    };
    ushort* h     = (ushort*)carve((size_t)N_NODES * HID * 2);
    ushort* X1    = (ushort*)carve((size_t)N_NODES * HID * 4);  // oversized: aliases etmp
    ushort* X2    = (ushort*)carve((size_t)N_NODES * HID * 2);
    ushort* X3    = (ushort*)carve((size_t)N_NODES * HID * 2);
    int*   bufA   = (int*)  carve((size_t)NH * 4);   // histT / cursorT
    int*   bufB   = (int*)  carve((size_t)NH * 4);   // histL (scanned)
    int*   row_ptr= (int*)  carve((size_t)(N_NODES + 1) * 4);
    int*   blkA   = (int*)  carve(1024 * 4);
    int*   blkB   = (int*)  carve(1024 * 4);
    int*   starts = (int*)  carve((N_GRAPHS + 1) * 4);
    float* sums   = (float*)carve(N_GRAPHS * HID * 4);
    ull*   edges  = (ull*)  carve((size_t)N_EDGES * 8);
    // etmp aliases X1: etmp dead (after bucket_sort) before spmm1 writes X1.
    ull*   etmp   = (ull*)X1;
    (void)ws_size; (void)in_sizes; (void)n_in; (void)out_size;

    // ---- build: hist[tile][bucket] -> transpose -> scan -> transpose ->
    //      bucket-grouped scatter -> per-bucket counting sort
    hist_pass<<<NTILES, 256, 0, stream>>>(rows, bufA);
    transpose_int<<<dim3((NBUCKET + 31) / 32, (NTILES + 31) / 32), dim3(32, 32), 0, stream>>>(bufA, bufB, NTILES, NBUCKET);
    scan_blocks<<<NSCAN1, 256, 0, stream>>>(bufB, bufB, blkA, NH);
    scan_blocks<<<1, 256, 0, stream>>>(blkA, blkA, blkB, NSCAN1);
    scan_add<<<(NH + 255) / 256, 256, 0, stream>>>(bufB, blkA, NH);
    transpose_int<<<dim3((NTILES + 31) / 32, (NBUCKET + 31) / 32), dim3(32, 32), 0, stream>>>(bufB, bufA, NBUCKET, NTILES);
    scatter_pass<<<NTILES, 256, 0, stream>>>(rows, cols, vals, bufA, etmp);
    bucket_sort<<<NBUCKET, 512, 0, stream>>>(bufB, etmp, edges, row_ptr);

    const int gemm_grid = (N_NODES + 63) / 64;   // 64 rows/block
    const int spmm_grid = (N_NODES + 3) / 4;

    // ---- layers (X_l kept separately; pooling sums them later)
    gemm_mfma<IN_DIM, float><<<gemm_grid, 256, 0, stream>>>(X, W1, b1, h);
    spmm_relu<<<spmm_grid, 256, 0, stream>>>(row_ptr, edges, h, X1);
    gemm_mfma<HID, ushort><<<gemm_grid, 256, 0, stream>>>(X1, W2, b2, h);
    spmm_relu<<<spmm_grid, 256, 0, stream>>>(row_ptr, edges, h, X2);
    gemm_mfma<HID, ushort><<<gemm_grid, 256, 0, stream>>>(X2, W3, b3, h);
    spmm_relu<<<spmm_grid, 256, 0, stream>>>(row_ptr, edges, h, X3);

    // ---- pool + head
    hipMemsetAsync(sums, 0, N_GRAPHS * HID * 4, stream);
    find_starts<<<1, 128, 0, stream>>>(batch, starts);
    pool_fused<<<(N_NODES + 127) / 128, 256, 0, stream>>>(X1, X2, X3, batch, sums);
    head_kernel<<<N_GRAPHS, 64, 0, stream>>>(sums, starts, Wout, bout, out);
}

// Round 8
// 509.928 us; speedup vs baseline: 8.8201x; 1.0128x over previous
//
#include <hip/hip_runtime.h>
#include <hip/hip_bf16.h>
#include <math.h>

#define N_NODES   100000
#define N_EDGES   3200000
#define IN_DIM    128
#define HID       64
#define OUT_DIM   10
#define N_GRAPHS  64

// Radix geometry: bucket = row >> 9 (512 rows/bucket), tile = 8192 edges.
// Run per (tile,bucket) = 8192*512/100000 ~= 42 edges = 336 B -> line amp
// ~1.19 (R7's 84 B runs gave 3.3x WRITE amplification).
#define BUCKET_SHIFT 9
#define BUCKET_ROWS  512
#define NBUCKET ((N_NODES + BUCKET_ROWS - 1) >> BUCKET_SHIFT)     // 196
#define TILE_EDGES 8192                                           // 256 thr x 32
#define NTILES ((N_EDGES + TILE_EDGES - 1) / TILE_EDGES)          // 391
#define NH (NBUCKET * NTILES)                                     // 76,636
#define NSCAN1 ((NH + 1023) / 1024)                               // 75

typedef unsigned long long ull;
typedef unsigned short ushort;
typedef __attribute__((ext_vector_type(8))) short short8;   // 8 bf16 (4 VGPRs)
typedef __attribute__((ext_vector_type(4))) float f32x4;    // MFMA C/D

__device__ __forceinline__ ushort rne_bf16(float x) {
    unsigned u = __float_as_uint(x);
    return (ushort)((u + 0x7fffu + ((u >> 16) & 1u)) >> 16);
}
__device__ __forceinline__ float bf2f(ushort u) {
    return __uint_as_float((unsigned)u << 16);
}

// ---------------------------------------------------------------- pass A
// Per-tile LDS histogram; write histT[tile][bucket] (coalesced).
__global__ __launch_bounds__(256) void hist_pass(const int* __restrict__ rows,
                                                 int* __restrict__ histT) {
    __shared__ int h[NBUCKET];
    int tid = threadIdx.x, tile = blockIdx.x;
    for (int i = tid; i < NBUCKET; i += 256) h[i] = 0;
    __syncthreads();
    int base = tile * TILE_EDGES;
#pragma unroll
    for (int i = 0; i < 32; i++) {
        int e = base + i * 256 + tid;
        if (e < N_EDGES) atomicAdd(&h[rows[e] >> BUCKET_SHIFT], 1);
    }
    __syncthreads();
    for (int i = tid; i < NBUCKET; i += 256) histT[tile * NBUCKET + i] = h[i];
}

// ---------------------------------------------------------------- transpose
__global__ __launch_bounds__(1024) void transpose_int(const int* __restrict__ in,
                                                      int* __restrict__ out,
                                                      int R, int C) {
    __shared__ int tile[32][33];
    int tx = threadIdx.x, ty = threadIdx.y;
    int r = blockIdx.y * 32 + ty, c = blockIdx.x * 32 + tx;
    if (r < R && c < C) tile[ty][tx] = in[r * C + c];
    __syncthreads();
    int rr = blockIdx.y * 32 + tx, cc = blockIdx.x * 32 + ty;
    if (cc < C && rr < R) out[cc * R + rr] = tile[tx][ty];
}

// ---------------------------------------------------------------- scan
__global__ __launch_bounds__(256) void scan_blocks(const int* __restrict__ in,
                                                   int* __restrict__ out,
                                                   int* __restrict__ blk, int n) {
    __shared__ int sdata[256];
    int t = threadIdx.x;
    int base = blockIdx.x * 1024 + t * 4;
    int v[4];
#pragma unroll
    for (int i = 0; i < 4; i++) {
        int idx = base + i;
        v[i] = (idx < n) ? in[idx] : 0;
    }
    int s = v[0] + v[1] + v[2] + v[3];
    sdata[t] = s;
    __syncthreads();
    for (int off = 1; off < 256; off <<= 1) {
        int x = (t >= off) ? sdata[t - off] : 0;
        __syncthreads();
        sdata[t] += x;
        __syncthreads();
    }
    int excl = sdata[t] - s;
#pragma unroll
    for (int i = 0; i < 4; i++) {
        int idx = base + i;
        if (idx < n) { out[idx] = excl; excl += v[i]; }
    }
    if (t == 255) blk[blockIdx.x] = sdata[255];
}

__global__ __launch_bounds__(256) void scan_add(int* __restrict__ data,
                                                const int* __restrict__ blk, int n) {
    int i = blockIdx.x * 256 + threadIdx.x;
    if (i < n) data[i] += blk[i >> 10];
}

// ---------------------------------------------------------------- pass B
// Re-read edges; LDS cursors from cursorT[tile][bucket]; write bucket-
// grouped packed records (rowLocal<<55.. fits: 9 bits). 336 B runs.
__global__ __launch_bounds__(256) void scatter_pass(const int* __restrict__ rows,
                                                    const int* __restrict__ cols,
                                                    const float* __restrict__ vals,
                                                    const int* __restrict__ cursorT,
                                                    ull* __restrict__ etmp) {
    __shared__ int cur[NBUCKET];
    int tid = threadIdx.x, tile = blockIdx.x;
    for (int i = tid; i < NBUCKET; i += 256) cur[i] = cursorT[tile * NBUCKET + i];
    __syncthreads();
    int base = tile * TILE_EDGES;
#pragma unroll
    for (int i = 0; i < 32; i++) {
        int e = base + i * 256 + tid;
        if (e < N_EDGES) {
            int r = rows[e];
            int b = r >> BUCKET_SHIFT;
            int pos = atomicAdd(&cur[b], 1);      // LDS atomic, block-local
            // pack: rowLocal(9b) << 55 | col(17b used of 23) << 32 | val
            unsigned hi = ((unsigned)(r & (BUCKET_ROWS - 1)) << 23) | (unsigned)cols[e];
            etmp[pos] = ((ull)hi << 32) | (ull)__float_as_uint(vals[e]);
        }
    }
}

// ---------------------------------------------------------------- pass C
// One 1024-thr block per 512-row bucket: counting-sort ~16.3k contiguous
// edges by local row; emit exact row_ptr + final packed edges (val<<32|col).
// Reads and writes both fully contiguous (write amp 1.0).
__global__ __launch_bounds__(1024) void bucket_sort(const int* __restrict__ histL,
                                                    const ull* __restrict__ etmp,
                                                    ull* __restrict__ edges,
                                                    int* __restrict__ row_ptr) {
    __shared__ int rcnt[BUCKET_ROWS];
    __shared__ int roff[BUCKET_ROWS];
    __shared__ int rcur[BUCKET_ROWS];
    int b = blockIdx.x, t = threadIdx.x;
    int s = histL[b * NTILES];
    int e = (b + 1 < NBUCKET) ? histL[(b + 1) * NTILES] : N_EDGES;
    if (t < BUCKET_ROWS) rcnt[t] = 0;
    __syncthreads();
    for (int j = s + t; j < e; j += 1024)
        atomicAdd(&rcnt[(int)(etmp[j] >> 55)], 1);
    __syncthreads();
    if (t < BUCKET_ROWS) roff[t] = rcnt[t];
    __syncthreads();
    for (int off = 1; off < BUCKET_ROWS; off <<= 1) {
        int x = (t >= off && t < BUCKET_ROWS) ? roff[t - off] : 0;
        __syncthreads();
        if (t < BUCKET_ROWS) roff[t] += x;
        __syncthreads();
    }
    if (t < BUCKET_ROWS) {
        int excl = roff[t] - rcnt[t];
        rcur[t] = s + excl;
        int grow = b * BUCKET_ROWS + t;
        if (grow < N_NODES) row_ptr[grow] = s + excl;
    }
    if (b == NBUCKET - 1 && t == 0) row_ptr[N_NODES] = N_EDGES;
    __syncthreads();
    for (int j = s + t; j < e; j += 1024) {
        ull p = etmp[j];
        int rl = (int)(p >> 55);
        unsigned col = (unsigned)(p >> 32) & 0x7FFFFFu;
        int pos = atomicAdd(&rcur[rl], 1);        // LDS atomic
        edges[pos] = ((p & 0xFFFFFFFFull) << 32) | (ull)col;
    }
}

// ------------------------------------------------------------------- GEMM
// MFMA bf16: H[M,64] = X[M,K] @ W[64,K]^T + b, output bf16. X read once.
template <int K, typename XT>
__global__ __launch_bounds__(256) void gemm_mfma(const XT* __restrict__ X,
                                                 const float* __restrict__ W,
                                                 const float* __restrict__ B,
                                                 ushort* __restrict__ H) {
    constexpr int KS = K / 32;
    int wave = threadIdx.x >> 6;
    int lane = threadIdx.x & 63;
    int quad = lane >> 4;
    int l16  = lane & 15;
    int rowBase = blockIdx.x * 64 + wave * 16;
    int arow = rowBase + l16;
    if (arow > N_NODES - 1) arow = N_NODES - 1;   // clamp OOB loads (stores guarded)

    short8 a[KS];
#pragma unroll
    for (int ks = 0; ks < KS; ks++) {
        int k = ks * 32 + quad * 8;
        if constexpr (sizeof(XT) == 2) {
            a[ks] = *reinterpret_cast<const short8*>(X + (size_t)arow * K + k);
        } else {
            const float4* src = reinterpret_cast<const float4*>(X + (size_t)arow * K + k);
            float4 t0 = src[0], t1 = src[1];
            union { short8 v; ushort u[8]; } cv;
            cv.u[0] = rne_bf16(t0.x); cv.u[1] = rne_bf16(t0.y);
            cv.u[2] = rne_bf16(t0.z); cv.u[3] = rne_bf16(t0.w);
            cv.u[4] = rne_bf16(t1.x); cv.u[5] = rne_bf16(t1.y);
            cv.u[6] = rne_bf16(t1.z); cv.u[7] = rne_bf16(t1.w);
            a[ks] = cv.v;
        }
    }

    f32x4 acc[4];
#pragma unroll
    for (int nt = 0; nt < 4; nt++) acc[nt] = 0.f;

#pragma unroll
    for (int nt = 0; nt < 4; nt++) {
        int brow = nt * 16 + l16;                 // W row = output channel n
#pragma unroll
        for (int ks = 0; ks < KS; ks++) {
            int k = ks * 32 + quad * 8;
            const float4* src = reinterpret_cast<const float4*>(W + brow * K + k);
            float4 t0 = src[0], t1 = src[1];
            union { short8 v; ushort u[8]; } cv;
            cv.u[0] = rne_bf16(t0.x); cv.u[1] = rne_bf16(t0.y);
            cv.u[2] = rne_bf16(t0.z); cv.u[3] = rne_bf16(t0.w);
            cv.u[4] = rne_bf16(t1.x); cv.u[5] = rne_bf16(t1.y);
            cv.u[6] = rne_bf16(t1.z); cv.u[7] = rne_bf16(t1.w);
            acc[nt] = __builtin_amdgcn_mfma_f32_16x16x32_bf16(a[ks], cv.v, acc[nt], 0, 0, 0);
        }
    }

#pragma unroll
    for (int nt = 0; nt < 4; nt++) {
        int n = nt * 16 + l16;
        float bv = B[n];
#pragma unroll
        for (int reg = 0; reg < 4; reg++) {
            int m = rowBase + quad * 4 + reg;
            if (m < N_NODES) H[(size_t)m * HID + n] = rne_bf16(acc[nt][reg] + bv);
        }
    }
}

// ------------------------------------------------------------------- SpMM
// Row-per-wave, lane = feature, bf16 gathers (128B/edge), 16-deep unroll.
__global__ __launch_bounds__(256) void spmm_relu(const int* __restrict__ row_ptr,
                                                 const ull* __restrict__ edges,
                                                 const ushort* __restrict__ Hin,
                                                 ushort* __restrict__ Xout) {
    int wid  = (blockIdx.x * 256 + threadIdx.x) >> 6;
    int lane = threadIdx.x & 63;
    if (wid >= N_NODES) return;
    int r = __builtin_amdgcn_readfirstlane(wid);  // wave-uniform -> s_loads
    int start = row_ptr[r];
    int end   = row_ptr[r + 1];
    float acc = 0.f;
    int e = start;
    for (; e + 16 <= end; e += 16) {
        ull p[16];
#pragma unroll
        for (int i = 0; i < 16; i++) p[i] = edges[e + i];
        float h[16];
#pragma unroll
        for (int i = 0; i < 16; i++) {
            int c = (int)(unsigned)(p[i] & 0xFFFFFFFFull);
            h[i] = bf2f(Hin[c * HID + lane]);
        }
#pragma unroll
        for (int i = 0; i < 16; i++) {
            float v = __uint_as_float((unsigned)(p[i] >> 32));
            acc += v * h[i];
        }
    }
    for (; e + 4 <= end; e += 4) {
        ull p[4];
#pragma unroll
        for (int i = 0; i < 4; i++) p[i] = edges[e + i];
#pragma unroll
        for (int i = 0; i < 4; i++) {
            int c = (int)(unsigned)(p[i] & 0xFFFFFFFFull);
            float v = __uint_as_float((unsigned)(p[i] >> 32));
            acc += v * bf2f(Hin[c * HID + lane]);
        }
    }
    for (; e < end; e++) {
        ull p = edges[e];
        int c = (int)(unsigned)(p & 0xFFFFFFFFull);
        float v = __uint_as_float((unsigned)(p >> 32));
        acc += v * bf2f(Hin[c * HID + lane]);
    }
    Xout[r * HID + lane] = rne_bf16(fmaxf(acc, 0.f));
}

// ------------------------------------------------------------------- Pool
__global__ __launch_bounds__(128) void find_starts(const int* __restrict__ batch,
                                                   int* __restrict__ starts) {
    int g = threadIdx.x;
    if (g > N_GRAPHS) return;
    if (g == N_GRAPHS) { starts[g] = N_NODES; return; }
    int lo = 0, hi = N_NODES;
    while (lo < hi) {
        int mid = (lo + hi) >> 1;
        if (batch[mid] < g) lo = mid + 1; else hi = mid;
    }
    starts[g] = lo;
}

// Segmented pool over X1+X2+X3 (bf16): lane = feature; batch sorted ->
// one atomicAdd per segment per wave.
__global__ __launch_bounds__(256) void pool_fused(const ushort* __restrict__ X1,
                                                  const ushort* __restrict__ X2,
                                                  const ushort* __restrict__ X3,
                                                  const int* __restrict__ batch,
                                                  float* __restrict__ sums) {
    int lane = threadIdx.x & 63;
    int w = threadIdx.x >> 6;
    int n0 = blockIdx.x * 128 + w * 32;
    if (n0 >= N_NODES) return;
    int n1 = n0 + 32;
    if (n1 > N_NODES) n1 = N_NODES;
    int g_cur = __builtin_amdgcn_readfirstlane(batch[n0]);
    float acc = 0.f;
    for (int n = n0; n < n1; n++) {
        int g = __builtin_amdgcn_readfirstlane(batch[n]);
        if (g != g_cur) {
            atomicAdd(&sums[g_cur * HID + lane], acc);
            acc = 0.f; g_cur = g;
        }
        size_t base = (size_t)n * HID + lane;
        acc += bf2f(X1[base]) + bf2f(X2[base]) + bf2f(X3[base]);
    }
    atomicAdd(&sums[g_cur * HID + lane], acc);
}

// ------------------------------------------------------------------- Head
__global__ __launch_bounds__(64) void head_kernel(const float* __restrict__ sums,
                                                  const int* __restrict__ starts,
                                                  const float* __restrict__ Wout,
                                                  const float* __restrict__ bout,
                                                  float* __restrict__ out) {
    int g = blockIdx.x;
    int t = threadIdx.x;
    __shared__ float pr[HID];
    __shared__ float lg[OUT_DIM];
    __shared__ float mx, sm;
    int cnt = starts[g + 1] - starts[g];
    float denom = 3.0f * (float)(cnt > 1 ? cnt : 1);
    pr[t] = sums[g * HID + t] / denom;
    __syncthreads();
    if (t < OUT_DIM) {
        float a = bout[t];
        for (int k = 0; k < HID; k++) a += pr[k] * Wout[t * HID + k];
        lg[t] = a;
    }
    __syncthreads();
    if (t == 0) {
        float m = lg[0];
        for (int j = 1; j < OUT_DIM; j++) m = fmaxf(m, lg[j]);
        float s = 0.f;
        for (int j = 0; j < OUT_DIM; j++) s += expf(lg[j] - m);
        mx = m; sm = s;
    }
    __syncthreads();
    if (t < OUT_DIM) out[g * OUT_DIM + t] = expf(lg[t] - mx) / sm;
}

// ---------------------------------------------------------------- launcher
extern "C" void kernel_launch(void* const* d_in, const int* in_sizes, int n_in,
                              void* d_out, int out_size, void* d_ws, size_t ws_size,
                              hipStream_t stream) {
    const float* X    = (const float*)d_in[0];
    const float* vals = (const float*)d_in[1];
    const float* W1   = (const float*)d_in[2];
    const float* b1   = (const float*)d_in[3];
    const float* W2   = (const float*)d_in[4];
    const float* b2   = (const float*)d_in[5];
    const float* W3   = (const float*)d_in[6];
    const float* b3   = (const float*)d_in[7];
    const float* Wout = (const float*)d_in[8];
    const float* bout = (const float*)d_in[9];
    const int*   rows = (const int*)d_in[10];
    const int*   cols = (const int*)d_in[11];
    const int*   batch= (const int*)d_in[12];
    float* out = (float*)d_out;

    char* p = (char*)d_ws;
    auto carve = [&](size_t bytes) {
        void* q = (void*)p;
        p += (bytes + 255) & ~(size_t)255;
        return q;
    };
    ushort* h     = (ushort*)carve((size_t)N_NODES * HID * 2);
    ushort* X1    = (ushort*)carve((size_t)N_NODES * HID * 4);  // oversized: aliases etmp
    ushort* X2    = (ushort*)carve((size_t)N_NODES * HID * 2);
    ushort* X3    = (ushort*)carve((size_t)N_NODES * HID * 2);
    int*   bufA   = (int*)  carve((size_t)NH * 4);   // histT / cursorT
    int*   bufB   = (int*)  carve((size_t)NH * 4);   // histL (scanned)
    int*   row_ptr= (int*)  carve((size_t)(N_NODES + 1) * 4);
    int*   blkA   = (int*)  carve(1024 * 4);
    int*   blkB   = (int*)  carve(1024 * 4);
    int*   starts = (int*)  carve((N_GRAPHS + 1) * 4);
    float* sums   = (float*)carve(N_GRAPHS * HID * 4);
    ull*   edges  = (ull*)  carve((size_t)N_EDGES * 8);
    // etmp aliases X1: etmp dead (after bucket_sort) before spmm1 writes X1.
    ull*   etmp   = (ull*)X1;
    (void)ws_size; (void)in_sizes; (void)n_in; (void)out_size;

    // ---- build: hist[tile][bucket] -> transpose -> scan -> transpose ->
    //      bucket-grouped scatter -> per-bucket counting sort
    hist_pass<<<NTILES, 256, 0, stream>>>(rows, bufA);
    transpose_int<<<dim3((NBUCKET + 31) / 32, (NTILES + 31) / 32), dim3(32, 32), 0, stream>>>(bufA, bufB, NTILES, NBUCKET);
    scan_blocks<<<NSCAN1, 256, 0, stream>>>(bufB, bufB, blkA, NH);
    scan_blocks<<<1, 256, 0, stream>>>(blkA, blkA, blkB, NSCAN1);
    scan_add<<<(NH + 255) / 256, 256, 0, stream>>>(bufB, blkA, NH);
    transpose_int<<<dim3((NTILES + 31) / 32, (NBUCKET + 31) / 32), dim3(32, 32), 0, stream>>>(bufB, bufA, NBUCKET, NTILES);
    scatter_pass<<<NTILES, 256, 0, stream>>>(rows, cols, vals, bufA, etmp);
    bucket_sort<<<NBUCKET, 1024, 0, stream>>>(bufB, etmp, edges, row_ptr);

    const int gemm_grid = (N_NODES + 63) / 64;   // 64 rows/block
    const int spmm_grid = (N_NODES + 3) / 4;

    // ---- layers (X_l kept separately; pooling sums them later)
    gemm_mfma<IN_DIM, float><<<gemm_grid, 256, 0, stream>>>(X, W1, b1, h);
    spmm_relu<<<spmm_grid, 256, 0, stream>>>(row_ptr, edges, h, X1);
    gemm_mfma<HID, ushort><<<gemm_grid, 256, 0, stream>>>(X1, W2, b2, h);
    spmm_relu<<<spmm_grid, 256, 0, stream>>>(row_ptr, edges, h, X2);
    gemm_mfma<HID, ushort><<<gemm_grid, 256, 0, stream>>>(X2, W3, b3, h);
    spmm_relu<<<spmm_grid, 256, 0, stream>>>(row_ptr, edges, h, X3);

    // ---- pool + head
    hipMemsetAsync(sums, 0, N_GRAPHS * HID * 4, stream);
    find_starts<<<1, 128, 0, stream>>>(batch, starts);
    pool_fused<<<(N_NODES + 127) / 128, 256, 0, stream>>>(X1, X2, X3, batch, sums);
    head_kernel<<<N_GRAPHS, 64, 0, stream>>>(sums, starts, Wout, bout, out);
}

// Round 9
// 496.411 us; speedup vs baseline: 9.0602x; 1.0272x over previous
//
#include <hip/hip_runtime.h>
#include <hip/hip_bf16.h>
#include <math.h>

#define N_NODES   100000
#define N_EDGES   3200000
#define IN_DIM    128
#define HID       64
#define OUT_DIM   10
#define N_GRAPHS  64

// Radix geometry: bucket = row >> 8 (256 rows/bucket), tile = 8192 edges.
// Run per (tile,bucket) ~= 21 edges = 168 B (amp ~1.4); NBUCKET=391 gives
// bucket_sort 2x the blocks of R8's 196.
#define BUCKET_SHIFT 8
#define BUCKET_ROWS  256
#define NBUCKET ((N_NODES + BUCKET_ROWS - 1) >> BUCKET_SHIFT)     // 391
#define TILE_EDGES 8192                                           // 1024 thr x 8
#define NTILES ((N_EDGES + TILE_EDGES - 1) / TILE_EDGES)          // 391
#define NH (NBUCKET * NTILES)                                     // 152,881
#define NSCAN1 ((NH + 1023) / 1024)                               // 150

typedef unsigned long long ull;
typedef unsigned short ushort;
typedef __attribute__((ext_vector_type(8))) short short8;   // 8 bf16 (4 VGPRs)
typedef __attribute__((ext_vector_type(4))) float f32x4;    // MFMA C/D

__device__ __forceinline__ ushort rne_bf16(float x) {
    unsigned u = __float_as_uint(x);
    return (ushort)((u + 0x7fffu + ((u >> 16) & 1u)) >> 16);
}
__device__ __forceinline__ float bf2f(ushort u) {
    return __uint_as_float((unsigned)u << 16);
}

// ---------------------------------------------------------------- pass A
// Per-tile LDS histogram; write histT[tile][bucket] (coalesced).
// 1024 thr x 8 iters: 4x waves of the R8 version (latency-bound pass).
__global__ __launch_bounds__(1024) void hist_pass(const int* __restrict__ rows,
                                                  int* __restrict__ histT) {
    __shared__ int h[NBUCKET];
    int tid = threadIdx.x, tile = blockIdx.x;
    for (int i = tid; i < NBUCKET; i += 1024) h[i] = 0;
    __syncthreads();
    int base = tile * TILE_EDGES;
#pragma unroll
    for (int i = 0; i < 8; i++) {
        int e = base + i * 1024 + tid;
        if (e < N_EDGES) atomicAdd(&h[rows[e] >> BUCKET_SHIFT], 1);
    }
    __syncthreads();
    for (int i = tid; i < NBUCKET; i += 1024) histT[tile * NBUCKET + i] = h[i];
}

// ---------------------------------------------------------------- transpose
__global__ __launch_bounds__(1024) void transpose_int(const int* __restrict__ in,
                                                      int* __restrict__ out,
                                                      int R, int C) {
    __shared__ int tile[32][33];
    int tx = threadIdx.x, ty = threadIdx.y;
    int r = blockIdx.y * 32 + ty, c = blockIdx.x * 32 + tx;
    if (r < R && c < C) tile[ty][tx] = in[r * C + c];
    __syncthreads();
    int rr = blockIdx.y * 32 + tx, cc = blockIdx.x * 32 + ty;
    if (cc < C && rr < R) out[cc * R + rr] = tile[tx][ty];
}

// ---------------------------------------------------------------- scan
__global__ __launch_bounds__(256) void scan_blocks(const int* __restrict__ in,
                                                   int* __restrict__ out,
                                                   int* __restrict__ blk, int n) {
    __shared__ int sdata[256];
    int t = threadIdx.x;
    int base = blockIdx.x * 1024 + t * 4;
    int v[4];
#pragma unroll
    for (int i = 0; i < 4; i++) {
        int idx = base + i;
        v[i] = (idx < n) ? in[idx] : 0;
    }
    int s = v[0] + v[1] + v[2] + v[3];
    sdata[t] = s;
    __syncthreads();
    for (int off = 1; off < 256; off <<= 1) {
        int x = (t >= off) ? sdata[t - off] : 0;
        __syncthreads();
        sdata[t] += x;
        __syncthreads();
    }
    int excl = sdata[t] - s;
#pragma unroll
    for (int i = 0; i < 4; i++) {
        int idx = base + i;
        if (idx < n) { out[idx] = excl; excl += v[i]; }
    }
    if (t == 255) blk[blockIdx.x] = sdata[255];
}

__global__ __launch_bounds__(256) void scan_add(int* __restrict__ data,
                                                const int* __restrict__ blk, int n) {
    int i = blockIdx.x * 256 + threadIdx.x;
    if (i < n) data[i] += blk[i >> 10];
}

// ---------------------------------------------------------------- pass B
// Re-read edges; LDS cursors from cursorT[tile][bucket]; write bucket-
// grouped packed records (rowLocal(8b)<<56 | col(17b)<<32 | val).
__global__ __launch_bounds__(1024) void scatter_pass(const int* __restrict__ rows,
                                                     const int* __restrict__ cols,
                                                     const float* __restrict__ vals,
                                                     const int* __restrict__ cursorT,
                                                     ull* __restrict__ etmp) {
    __shared__ int cur[NBUCKET];
    int tid = threadIdx.x, tile = blockIdx.x;
    for (int i = tid; i < NBUCKET; i += 1024) cur[i] = cursorT[tile * NBUCKET + i];
    __syncthreads();
    int base = tile * TILE_EDGES;
#pragma unroll
    for (int i = 0; i < 8; i++) {
        int e = base + i * 1024 + tid;
        if (e < N_EDGES) {
            int r = rows[e];
            int b = r >> BUCKET_SHIFT;
            int pos = atomicAdd(&cur[b], 1);      // LDS atomic, block-local
            unsigned hi = ((unsigned)(r & (BUCKET_ROWS - 1)) << 24) | (unsigned)cols[e];
            etmp[pos] = ((ull)hi << 32) | (ull)__float_as_uint(vals[e]);
        }
    }
}

// ---------------------------------------------------------------- pass C
// One 512-thr block per 256-row bucket: counting-sort ~8.2k contiguous
// edges by local row; emit exact row_ptr + final packed edges (val<<32|col).
__global__ __launch_bounds__(512) void bucket_sort(const int* __restrict__ histL,
                                                   const ull* __restrict__ etmp,
                                                   ull* __restrict__ edges,
                                                   int* __restrict__ row_ptr) {
    __shared__ int rcnt[BUCKET_ROWS];
    __shared__ int roff[BUCKET_ROWS];
    __shared__ int rcur[BUCKET_ROWS];
    int b = blockIdx.x, t = threadIdx.x;
    int s = histL[b * NTILES];
    int e = (b + 1 < NBUCKET) ? histL[(b + 1) * NTILES] : N_EDGES;
    if (t < BUCKET_ROWS) rcnt[t] = 0;
    __syncthreads();
    for (int j = s + t; j < e; j += 512)
        atomicAdd(&rcnt[(int)(etmp[j] >> 56)], 1);
    __syncthreads();
    if (t < BUCKET_ROWS) roff[t] = rcnt[t];
    __syncthreads();
    for (int off = 1; off < BUCKET_ROWS; off <<= 1) {
        int x = (t >= off && t < BUCKET_ROWS) ? roff[t - off] : 0;
        __syncthreads();
        if (t < BUCKET_ROWS) roff[t] += x;
        __syncthreads();
    }
    if (t < BUCKET_ROWS) {
        int excl = roff[t] - rcnt[t];
        rcur[t] = s + excl;
        int grow = b * BUCKET_ROWS + t;
        if (grow < N_NODES) row_ptr[grow] = s + excl;
    }
    if (b == NBUCKET - 1 && t == 0) row_ptr[N_NODES] = N_EDGES;
    __syncthreads();
    for (int j = s + t; j < e; j += 512) {
        ull p = etmp[j];
        int rl = (int)(p >> 56);
        unsigned col = (unsigned)(p >> 32) & 0xFFFFFFu;
        int pos = atomicAdd(&rcur[rl], 1);        // LDS atomic
        edges[pos] = ((p & 0xFFFFFFFFull) << 32) | (ull)col;
    }
}

// ------------------------------------------------------------------- GEMM
// MFMA bf16: H[M,64] = X[M,K] @ W[64,K]^T + b, output bf16. X read once.
template <int K, typename XT>
__global__ __launch_bounds__(256) void gemm_mfma(const XT* __restrict__ X,
                                                 const float* __restrict__ W,
                                                 const float* __restrict__ B,
                                                 ushort* __restrict__ H) {
    constexpr int KS = K / 32;
    int wave = threadIdx.x >> 6;
    int lane = threadIdx.x & 63;
    int quad = lane >> 4;
    int l16  = lane & 15;
    int rowBase = blockIdx.x * 64 + wave * 16;
    int arow = rowBase + l16;
    if (arow > N_NODES - 1) arow = N_NODES - 1;   // clamp OOB loads (stores guarded)

    short8 a[KS];
#pragma unroll
    for (int ks = 0; ks < KS; ks++) {
        int k = ks * 32 + quad * 8;
        if constexpr (sizeof(XT) == 2) {
            a[ks] = *reinterpret_cast<const short8*>(X + (size_t)arow * K + k);
        } else {
            const float4* src = reinterpret_cast<const float4*>(X + (size_t)arow * K + k);
            float4 t0 = src[0], t1 = src[1];
            union { short8 v; ushort u[8]; } cv;
            cv.u[0] = rne_bf16(t0.x); cv.u[1] = rne_bf16(t0.y);
            cv.u[2] = rne_bf16(t0.z); cv.u[3] = rne_bf16(t0.w);
            cv.u[4] = rne_bf16(t1.x); cv.u[5] = rne_bf16(t1.y);
            cv.u[6] = rne_bf16(t1.z); cv.u[7] = rne_bf16(t1.w);
            a[ks] = cv.v;
        }
    }

    f32x4 acc[4];
#pragma unroll
    for (int nt = 0; nt < 4; nt++) acc[nt] = 0.f;

#pragma unroll
    for (int nt = 0; nt < 4; nt++) {
        int brow = nt * 16 + l16;                 // W row = output channel n
#pragma unroll
        for (int ks = 0; ks < KS; ks++) {
            int k = ks * 32 + quad * 8;
            const float4* src = reinterpret_cast<const float4*>(W + brow * K + k);
            float4 t0 = src[0], t1 = src[1];
            union { short8 v; ushort u[8]; } cv;
            cv.u[0] = rne_bf16(t0.x); cv.u[1] = rne_bf16(t0.y);
            cv.u[2] = rne_bf16(t0.z); cv.u[3] = rne_bf16(t0.w);
            cv.u[4] = rne_bf16(t1.x); cv.u[5] = rne_bf16(t1.y);
            cv.u[6] = rne_bf16(t1.z); cv.u[7] = rne_bf16(t1.w);
            acc[nt] = __builtin_amdgcn_mfma_f32_16x16x32_bf16(a[ks], cv.v, acc[nt], 0, 0, 0);
        }
    }

#pragma unroll
    for (int nt = 0; nt < 4; nt++) {
        int n = nt * 16 + l16;
        float bv = B[n];
#pragma unroll
        for (int reg = 0; reg < 4; reg++) {
            int m = rowBase + quad * 4 + reg;
            if (m < N_NODES) H[(size_t)m * HID + n] = rne_bf16(acc[nt][reg] + bv);
        }
    }
}

// ------------------------------------------------------------------- SpMM
// Row-per-wave, lane = feature, bf16 gathers (128B/edge), 16-deep unroll.
__global__ __launch_bounds__(256) void spmm_relu(const int* __restrict__ row_ptr,
                                                 const ull* __restrict__ edges,
                                                 const ushort* __restrict__ Hin,
                                                 ushort* __restrict__ Xout) {
    int wid  = (blockIdx.x * 256 + threadIdx.x) >> 6;
    int lane = threadIdx.x & 63;
    if (wid >= N_NODES) return;
    int r = __builtin_amdgcn_readfirstlane(wid);  // wave-uniform -> s_loads
    int start = row_ptr[r];
    int end   = row_ptr[r + 1];
    float acc = 0.f;
    int e = start;
    for (; e + 16 <= end; e += 16) {
        ull p[16];
#pragma unroll
        for (int i = 0; i < 16; i++) p[i] = edges[e + i];
        float h[16];
#pragma unroll
        for (int i = 0; i < 16; i++) {
            int c = (int)(unsigned)(p[i] & 0xFFFFFFFFull);
            h[i] = bf2f(Hin[c * HID + lane]);
        }
#pragma unroll
        for (int i = 0; i < 16; i++) {
            float v = __uint_as_float((unsigned)(p[i] >> 32));
            acc += v * h[i];
        }
    }
    for (; e + 4 <= end; e += 4) {
        ull p[4];
#pragma unroll
        for (int i = 0; i < 4; i++) p[i] = edges[e + i];
#pragma unroll
        for (int i = 0; i < 4; i++) {
            int c = (int)(unsigned)(p[i] & 0xFFFFFFFFull);
            float v = __uint_as_float((unsigned)(p[i] >> 32));
            acc += v * bf2f(Hin[c * HID + lane]);
        }
    }
    for (; e < end; e++) {
        ull p = edges[e];
        int c = (int)(unsigned)(p & 0xFFFFFFFFull);
        float v = __uint_as_float((unsigned)(p >> 32));
        acc += v * bf2f(Hin[c * HID + lane]);
    }
    Xout[r * HID + lane] = rne_bf16(fmaxf(acc, 0.f));
}

// ------------------------------------------------------------------- Pool
// Segmented pool over X1+X2+X3 (bf16): lane = feature; batch sorted ->
// one atomicAdd per segment per wave.
__global__ __launch_bounds__(256) void pool_fused(const ushort* __restrict__ X1,
                                                  const ushort* __restrict__ X2,
                                                  const ushort* __restrict__ X3,
                                                  const int* __restrict__ batch,
                                                  float* __restrict__ sums) {
    int lane = threadIdx.x & 63;
    int w = threadIdx.x >> 6;
    int n0 = blockIdx.x * 128 + w * 32;
    if (n0 >= N_NODES) return;
    int n1 = n0 + 32;
    if (n1 > N_NODES) n1 = N_NODES;
    int g_cur = __builtin_amdgcn_readfirstlane(batch[n0]);
    float acc = 0.f;
    for (int n = n0; n < n1; n++) {
        int g = __builtin_amdgcn_readfirstlane(batch[n]);
        if (g != g_cur) {
            atomicAdd(&sums[g_cur * HID + lane], acc);
            acc = 0.f; g_cur = g;
        }
        size_t base = (size_t)n * HID + lane;
        acc += bf2f(X1[base]) + bf2f(X2[base]) + bf2f(X3[base]);
    }
    atomicAdd(&sums[g_cur * HID + lane], acc);
}

// ------------------------------------------------------------------- Head
// Inline binary search for graph boundaries (find_starts folded in).
__global__ __launch_bounds__(64) void head_kernel(const float* __restrict__ sums,
                                                  const int* __restrict__ batch,
                                                  const float* __restrict__ Wout,
                                                  const float* __restrict__ bout,
                                                  float* __restrict__ out) {
    int g = blockIdx.x;
    int t = threadIdx.x;
    __shared__ float pr[HID];
    __shared__ float lg[OUT_DIM];
    __shared__ float mx, sm;
    auto lb = [&](int key) {
        int lo = 0, hi = N_NODES;
        while (lo < hi) {
            int mid = (lo + hi) >> 1;
            if (batch[mid] < key) lo = mid + 1; else hi = mid;
        }
        return lo;
    };
    int cnt = lb(g + 1) - lb(g);
    float denom = 3.0f * (float)(cnt > 1 ? cnt : 1);
    pr[t] = sums[g * HID + t] / denom;
    __syncthreads();
    if (t < OUT_DIM) {
        float a = bout[t];
        for (int k = 0; k < HID; k++) a += pr[k] * Wout[t * HID + k];
        lg[t] = a;
    }
    __syncthreads();
    if (t == 0) {
        float m = lg[0];
        for (int j = 1; j < OUT_DIM; j++) m = fmaxf(m, lg[j]);
        float s = 0.f;
        for (int j = 0; j < OUT_DIM; j++) s += expf(lg[j] - m);
        mx = m; sm = s;
    }
    __syncthreads();
    if (t < OUT_DIM) out[g * OUT_DIM + t] = expf(lg[t] - mx) / sm;
}

// ---------------------------------------------------------------- launcher
extern "C" void kernel_launch(void* const* d_in, const int* in_sizes, int n_in,
                              void* d_out, int out_size, void* d_ws, size_t ws_size,
                              hipStream_t stream) {
    const float* X    = (const float*)d_in[0];
    const float* vals = (const float*)d_in[1];
    const float* W1   = (const float*)d_in[2];
    const float* b1   = (const float*)d_in[3];
    const float* W2   = (const float*)d_in[4];
    const float* b2   = (const float*)d_in[5];
    const float* W3   = (const float*)d_in[6];
    const float* b3   = (const float*)d_in[7];
    const float* Wout = (const float*)d_in[8];
    const float* bout = (const float*)d_in[9];
    const int*   rows = (const int*)d_in[10];
    const int*   cols = (const int*)d_in[11];
    const int*   batch= (const int*)d_in[12];
    float* out = (float*)d_out;

    char* p = (char*)d_ws;
    auto carve = [&](size_t bytes) {
        void* q = (void*)p;
        p += (bytes + 255) & ~(size_t)255;
        return q;
    };
    ushort* h     = (ushort*)carve((size_t)N_NODES * HID * 2);
    ushort* X1    = (ushort*)carve((size_t)N_NODES * HID * 4);  // oversized: aliases etmp
    ushort* X2    = (ushort*)carve((size_t)N_NODES * HID * 2);
    ushort* X3    = (ushort*)carve((size_t)N_NODES * HID * 2);
    int*   bufA   = (int*)  carve((size_t)NH * 4);   // histT / cursorT
    int*   bufB   = (int*)  carve((size_t)NH * 4);   // histL (scanned)
    int*   row_ptr= (int*)  carve((size_t)(N_NODES + 1) * 4);
    int*   blkA   = (int*)  carve(1024 * 4);
    int*   blkB   = (int*)  carve(1024 * 4);
    float* sums   = (float*)carve(N_GRAPHS * HID * 4);
    ull*   edges  = (ull*)  carve((size_t)N_EDGES * 8);
    // etmp aliases X1: etmp dead (after bucket_sort) before spmm1 writes X1.
    ull*   etmp   = (ull*)X1;
    (void)ws_size; (void)in_sizes; (void)n_in; (void)out_size;

    // ---- build: hist[tile][bucket] -> transpose -> scan -> transpose ->
    //      bucket-grouped scatter -> per-bucket counting sort
    hist_pass<<<NTILES, 1024, 0, stream>>>(rows, bufA);
    transpose_int<<<dim3((NBUCKET + 31) / 32, (NTILES + 31) / 32), dim3(32, 32), 0, stream>>>(bufA, bufB, NTILES, NBUCKET);
    scan_blocks<<<NSCAN1, 256, 0, stream>>>(bufB, bufB, blkA, NH);
    scan_blocks<<<1, 256, 0, stream>>>(blkA, blkA, blkB, NSCAN1);
    scan_add<<<(NH + 255) / 256, 256, 0, stream>>>(bufB, blkA, NH);
    transpose_int<<<dim3((NTILES + 31) / 32, (NBUCKET + 31) / 32), dim3(32, 32), 0, stream>>>(bufB, bufA, NBUCKET, NTILES);
    scatter_pass<<<NTILES, 1024, 0, stream>>>(rows, cols, vals, bufA, etmp);
    bucket_sort<<<NBUCKET, 512, 0, stream>>>(bufB, etmp, edges, row_ptr);

    const int gemm_grid = (N_NODES + 63) / 64;   // 64 rows/block
    const int spmm_grid = (N_NODES + 3) / 4;

    // ---- layers (X_l kept separately; pooling sums them later)
    gemm_mfma<IN_DIM, float><<<gemm_grid, 256, 0, stream>>>(X, W1, b1, h);
    spmm_relu<<<spmm_grid, 256, 0, stream>>>(row_ptr, edges, h, X1);
    gemm_mfma<HID, ushort><<<gemm_grid, 256, 0, stream>>>(X1, W2, b2, h);
    spmm_relu<<<spmm_grid, 256, 0, stream>>>(row_ptr, edges, h, X2);
    gemm_mfma<HID, ushort><<<gemm_grid, 256, 0, stream>>>(X2, W3, b3, h);
    spmm_relu<<<spmm_grid, 256, 0, stream>>>(row_ptr, edges, h, X3);

    // ---- pool + head
    hipMemsetAsync(sums, 0, N_GRAPHS * HID * 4, stream);
    pool_fused<<<(N_NODES + 127) / 128, 256, 0, stream>>>(X1, X2, X3, batch, sums);
    head_kernel<<<N_GRAPHS, 64, 0, stream>>>(sums, batch, Wout, bout, out);
}